// Round 2
// baseline (1197.779 us; speedup 1.0000x reference)
//
#include <hip/hip_runtime.h>

#define DIMX 4096
#define DVX  1024
#define HX   16
#define DHX  64
#define NSX  32
#define BX   8
#define LX   2048
#define EPSF 1e-5f

typedef unsigned short u16;
typedef unsigned int   u32;

using bf16x8 = __attribute__((ext_vector_type(8))) __bf16;
using f32x4  = __attribute__((ext_vector_type(4))) float;

__device__ __forceinline__ float bfu(u16 u) {
    union { u32 i; float f; } c; c.i = ((u32)u) << 16; return c.f;
}
__device__ __forceinline__ u16 f2b(float f) {
    union { float f; u32 u; } c; c.f = f;
    u32 u = c.u;
    u32 r = (u + 0x7fffu + ((u >> 16) & 1u)) >> 16;
    return (u16)r;
}

// async global->LDS DMA, 16B per lane; LDS dest = wave-uniform base + lane*16
__device__ __forceinline__ void async16(const u16* g, u16* l) {
    __builtin_amdgcn_global_load_lds(
        (const __attribute__((address_space(1))) void*)g,
        (__attribute__((address_space(3))) void*)l, 16, 0, 0);
}

// load 8 logical elements (idx multiple of 8, 16B-aligned base) as fp32
template<bool ISF>
__device__ __forceinline__ void ld8(const void* base, size_t idx, float o[8]) {
    if (ISF) {
        const float* f = (const float*)base + idx;
        float4 a = *(const float4*)f, b = *(const float4*)(f + 4);
        o[0]=a.x; o[1]=a.y; o[2]=a.z; o[3]=a.w;
        o[4]=b.x; o[5]=b.y; o[6]=b.z; o[7]=b.w;
    } else {
        const u16* h = (const u16*)base + idx;
        uint4 v = *(const uint4*)h;
        o[0]=bfu(v.x & 0xffff); o[1]=bfu(v.x >> 16);
        o[2]=bfu(v.y & 0xffff); o[3]=bfu(v.y >> 16);
        o[4]=bfu(v.z & 0xffff); o[5]=bfu(v.z >> 16);
        o[6]=bfu(v.w & 0xffff); o[7]=bfu(v.w >> 16);
    }
}
__device__ __forceinline__ float ld1(const void* base, size_t idx, bool isf) {
    return isf ? ((const float*)base)[idx] : bfu(((const u16*)base)[idx]);
}

// ---------------- K0: dtype detector -------------------------------------
__global__ __launch_bounds__(256) void detect_kernel(const u16* __restrict__ X,
                                                     int* __restrict__ flag) {
    __shared__ int cnt;
    if (threadIdx.x == 0) cnt = 0;
    __syncthreads();
    int local = 0;
    for (int i = threadIdx.x; i < 8192; i += 256) {
        u32 e = ((u32)X[i] >> 7) & 0xffu;
        if (e >= 200u) local++;
    }
    atomicAdd(&cnt, local);
    __syncthreads();
    if (threadIdx.x == 0) *flag = (cnt > 32) ? 1 : 0;
}

// ---------------- K0b: fp32 -> bf16 bulk converter -------------------------
__global__ __launch_bounds__(256) void cvt_kernel(const int* __restrict__ flag,
                                                  const float* __restrict__ src,
                                                  u16* __restrict__ dst, int ngrp) {
    if (*flag == 0) return;
    int stride = gridDim.x * 256;
    for (int i = blockIdx.x * 256 + threadIdx.x; i < ngrp; i += stride) {
        const float4* f = (const float4*)(src + (size_t)i * 8);
        float4 a = f[0], b = f[1];
        uint4 r;
        r.x = (u32)f2b(a.x) | ((u32)f2b(a.y) << 16);
        r.y = (u32)f2b(a.z) | ((u32)f2b(a.w) << 16);
        r.z = (u32)f2b(b.x) | ((u32)f2b(b.y) << 16);
        r.w = (u32)f2b(b.z) | ((u32)f2b(b.w) << 16);
        *(uint4*)(dst + (size_t)i * 8) = r;
    }
}

// ---------------- K1: Qp = S @ Wq^T + bq  -- wave-per-output GEMV ----------
// Old version: thread-per-output with per-lane 4KB row walks = 64-way
// uncoalesced. Now: wave w of block computes one output; 64 lanes split the
// 1024-dot (16 elems/lane, coalesced) + 6-step shuffle reduce.
__global__ __launch_bounds__(256) void qp_kernel(
        const int* __restrict__ flag, const void* __restrict__ S,
        const void* __restrict__ Wq, const void* __restrict__ bq,
        float* __restrict__ Qp) {
    int wid = blockIdx.x * 4 + (threadIdx.x >> 6);   // 0..32767
    int lane = threadIdx.x & 63;
    int q = wid >> 10, n = wid & 1023;
    bool isf = (*flag != 0);
    float p = 0.f;
    if (isf) {
        const float* srow = (const float*)S + (size_t)q * DVX + lane * 16;
        const float* wrow = (const float*)Wq + (size_t)n * DVX + lane * 16;
#pragma unroll
        for (int e = 0; e < 16; e += 4) {
            float4 a = *(const float4*)(srow + e);
            float4 b = *(const float4*)(wrow + e);
            p += a.x * b.x + a.y * b.y + a.z * b.z + a.w * b.w;
        }
    } else {
        const u16* srow = (const u16*)S + (size_t)q * DVX + lane * 16;
        const u16* wrow = (const u16*)Wq + (size_t)n * DVX + lane * 16;
#pragma unroll
        for (int c = 0; c < 2; c++) {
            uint4 a = *(const uint4*)(srow + c * 8);
            uint4 b = *(const uint4*)(wrow + c * 8);
            p += bfu(a.x & 0xffff) * bfu(b.x & 0xffff) + bfu(a.x >> 16) * bfu(b.x >> 16)
               + bfu(a.y & 0xffff) * bfu(b.y & 0xffff) + bfu(a.y >> 16) * bfu(b.y >> 16)
               + bfu(a.z & 0xffff) * bfu(b.z & 0xffff) + bfu(a.z >> 16) * bfu(b.z >> 16)
               + bfu(a.w & 0xffff) * bfu(b.w & 0xffff) + bfu(a.w >> 16) * bfu(b.w >> 16);
        }
    }
#pragma unroll
    for (int off = 32; off > 0; off >>= 1)
        p += __shfl_xor(p, off, 64);
    if (lane == 0) Qp[wid] = p + ld1(bq, n, isf);
}

// ---------------- K2: fused K/V projection GEMM (m97 + XCD + LDS swizzle) --
#define TM 128
#define TN 128
#define BKK 32
#define LDT 32

__device__ __forceinline__ uint4 pack8(float o[8]) {
    uint4 r;
    r.x = (u32)f2b(o[0]) | ((u32)f2b(o[1]) << 16);
    r.y = (u32)f2b(o[2]) | ((u32)f2b(o[3]) << 16);
    r.z = (u32)f2b(o[4]) | ((u32)f2b(o[5]) << 16);
    r.w = (u32)f2b(o[6]) | ((u32)f2b(o[7]) << 16);
    return r;
}

// -------- fast path: bf16 inputs (native or pre-converted), DMA staging ----
__global__ __launch_bounds__(256) void kv_gemm2(
        const int* __restrict__ flag,
        const void* __restrict__ X,  const u16* __restrict__ Xb,
        const void* __restrict__ Wk, const void* __restrict__ bk,
        const void* __restrict__ Wv, const void* __restrict__ bv,
        const u16* __restrict__ Wkb, const u16* __restrict__ Wvb,
        u16* __restrict__ Kp, u16* __restrict__ Vp) {
    __shared__ u16 As[TM * LDT];
    __shared__ u16 Bs[TN * LDT];
    const bool isf = (*flag != 0);
    const u16* Xs = isf ? Xb : (const u16*)X;

    const int t = threadIdx.x;
    const int lane = t & 63, w = t >> 6;
    const int wm = w >> 1, wn = w & 1;
    const int quad = lane >> 4, l16 = lane & 15;
    const int bl = blockIdx.x;
    const int xcd = bl & 7, bq = bl >> 3;
    const int m0 = (xcd + 8 * (bq >> 4)) * TM;
    const int n0 = (bq & 15) * TN;
    const u16* Wb16; const void* bias; int boff;
    if (n0 < DVX) { Wb16 = (isf ? Wkb : (const u16*)Wk) + (size_t)n0 * DIMX;
                    bias = bk; boff = n0; }
    else          { Wb16 = (isf ? Wvb : (const u16*)Wv) + (size_t)(n0 - DVX) * DIMX;
                    bias = bv; boff = n0 - DVX; }

    f32x4 acc[4][4];
#pragma unroll
    for (int i = 0; i < 4; i++)
#pragma unroll
        for (int j = 0; j < 4; j++) acc[i][j] = {0.f, 0.f, 0.f, 0.f};

    // LDS chunk swizzle: LDS chunk c of row r holds global chunk c^((r>>1)&3)
    const int srow = lane >> 2;
    const int gcol = ((lane & 3) ^ ((lane >> 3) & 3)) * 8;
    const int ph = (l16 >> 1) & 3;

    for (int k0 = 0; k0 < DIMX; k0 += BKK) {
        __syncthreads();
#pragma unroll
        for (int c = 0; c < 2; c++) {
            int rr = w * 32 + c * 16;
            async16(Xs + (size_t)(m0 + rr + srow) * DIMX + k0 + gcol,
                    As + rr * LDT);
            async16(Wb16 + (size_t)(rr + srow) * DIMX + k0 + gcol,
                    Bs + rr * LDT);
        }
        __syncthreads();
        bf16x8 af[4], bfr[4];
#pragma unroll
        for (int mi = 0; mi < 4; mi++) {
            int ar = wm * 64 + mi * 16 + l16;
            af[mi] = *(const bf16x8*)&As[ar * LDT + (quad ^ ph) * 8];
        }
#pragma unroll
        for (int ni = 0; ni < 4; ni++) {
            int br = wn * 64 + ni * 16 + l16;
            bfr[ni] = *(const bf16x8*)&Bs[br * LDT + (quad ^ ph) * 8];
        }
#pragma unroll
        for (int mi = 0; mi < 4; mi++)
#pragma unroll
            for (int ni = 0; ni < 4; ni++)
                acc[mi][ni] = __builtin_amdgcn_mfma_f32_16x16x32_bf16(
                    af[mi], bfr[ni], acc[mi][ni], 0, 0, 0);
    }

    // D layout (m89-verified): col = lane&15 (n), row = quad*4+reg (m)
#pragma unroll
    for (int mi = 0; mi < 4; mi++) {
#pragma unroll
        for (int ni = 0; ni < 4; ni++) {
            int colL = wn * 64 + ni * 16 + l16;
            int col = n0 + colL;
            float bb = ld1(bias, (size_t)(boff + colL), isf);
            u16* dst; int dcol;
            if (col < DVX) { dst = Kp; dcol = col; }
            else           { dst = Vp; dcol = col - DVX; }
#pragma unroll
            for (int r = 0; r < 4; r++) {
                int row = m0 + wm * 64 + mi * 16 + quad * 4 + r;
                dst[(size_t)row * DVX + dcol] = f2b(acc[mi][ni][r] + bb);
            }
        }
    }
}

// -------- fallback path (small workspace): original dual-dtype body --------
template<bool ISF>
__device__ void kv_body(const void* __restrict__ X,
                        const void* __restrict__ Wk, const void* __restrict__ bk,
                        const void* __restrict__ Wv, const void* __restrict__ bv,
                        u16* __restrict__ Kp, u16* __restrict__ Vp,
                        u16* As, u16* Bs) {
    const int t = threadIdx.x;
    const int lane = t & 63, w = t >> 6;
    const int wm = w >> 1, wn = w & 1;
    const int quad = lane >> 4, l16 = lane & 15;
    const int bl = blockIdx.x;
    const int xcd = bl & 7, bq = bl >> 3;
    const int m0 = (xcd + 8 * (bq >> 4)) * TM;
    const int n0 = (bq & 15) * TN;
    const void* Wbase; const void* bias; int boff;
    size_t woff;
    if (n0 < DVX) { Wbase = Wk; bias = bk; woff = (size_t)n0 * DIMX; boff = n0; }
    else          { Wbase = Wv; bias = bv; woff = (size_t)(n0 - DVX) * DIMX; boff = n0 - DVX; }
    const u16* Wb16 = (const u16*)Wbase + woff;
    const float* Wbf = (const float*)Wbase + woff;

    f32x4 acc[4][4];
#pragma unroll
    for (int i = 0; i < 4; i++)
#pragma unroll
        for (int j = 0; j < 4; j++) acc[i][j] = {0.f, 0.f, 0.f, 0.f};

    const int srow = lane >> 2;
    const int gcol = ((lane & 3) ^ ((lane >> 3) & 3)) * 8;
    const int ph = (l16 >> 1) & 3;
    const int r0 = t >> 2, c0 = (t & 3) * 8;
    const int r1 = r0 + 64;
    const int swc = (((t & 3) ^ ((r0 >> 1) & 3))) * 8;

    for (int k0 = 0; k0 < DIMX; k0 += BKK) {
        if constexpr (ISF) {
            float oa0[8], oa1[8], ob0[8], ob1[8];
            ld8<true>(X,   (size_t)(m0 + r0) * DIMX + k0 + c0, oa0);
            ld8<true>(X,   (size_t)(m0 + r1) * DIMX + k0 + c0, oa1);
            ld8<true>(Wbf, (size_t)r0 * DIMX + k0 + c0, ob0);
            ld8<true>(Wbf, (size_t)r1 * DIMX + k0 + c0, ob1);
            __syncthreads();
            *(uint4*)&As[r0 * LDT + swc] = pack8(oa0);
            *(uint4*)&As[r1 * LDT + swc] = pack8(oa1);
            *(uint4*)&Bs[r0 * LDT + swc] = pack8(ob0);
            *(uint4*)&Bs[r1 * LDT + swc] = pack8(ob1);
        } else {
            __syncthreads();
#pragma unroll
            for (int c = 0; c < 2; c++) {
                int rr = w * 32 + c * 16;
                async16((const u16*)X + (size_t)(m0 + rr + srow) * DIMX + k0 + gcol,
                        As + rr * LDT);
                async16(Wb16 + (size_t)(rr + srow) * DIMX + k0 + gcol,
                        Bs + rr * LDT);
            }
        }
        __syncthreads();
        bf16x8 af[4], bfr[4];
#pragma unroll
        for (int mi = 0; mi < 4; mi++) {
            int ar = wm * 64 + mi * 16 + l16;
            af[mi] = *(const bf16x8*)&As[ar * LDT + (quad ^ ph) * 8];
        }
#pragma unroll
        for (int ni = 0; ni < 4; ni++) {
            int br = wn * 64 + ni * 16 + l16;
            bfr[ni] = *(const bf16x8*)&Bs[br * LDT + (quad ^ ph) * 8];
        }
#pragma unroll
        for (int mi = 0; mi < 4; mi++)
#pragma unroll
            for (int ni = 0; ni < 4; ni++)
                acc[mi][ni] = __builtin_amdgcn_mfma_f32_16x16x32_bf16(
                    af[mi], bfr[ni], acc[mi][ni], 0, 0, 0);
    }

#pragma unroll
    for (int mi = 0; mi < 4; mi++) {
#pragma unroll
        for (int ni = 0; ni < 4; ni++) {
            int colL = wn * 64 + ni * 16 + l16;
            int col = n0 + colL;
            float bb = ld1(bias, (size_t)(boff + colL), ISF);
            u16* dst; int dcol;
            if (col < DVX) { dst = Kp; dcol = col; }
            else           { dst = Vp; dcol = col - DVX; }
#pragma unroll
            for (int r = 0; r < 4; r++) {
                int row = m0 + wm * 64 + mi * 16 + quad * 4 + r;
                dst[(size_t)row * DVX + dcol] = f2b(acc[mi][ni][r] + bb);
            }
        }
    }
}

__global__ __launch_bounds__(256) void kv_gemm(
        const int* __restrict__ flag, const void* __restrict__ X,
        const void* __restrict__ Wk, const void* __restrict__ bk,
        const void* __restrict__ Wv, const void* __restrict__ bv,
        u16* __restrict__ Kp, u16* __restrict__ Vp) {
    __shared__ u16 As[TM * LDT];
    __shared__ u16 Bs[TN * LDT];
    if (*flag) kv_body<true>(X, Wk, bk, Wv, bv, Kp, Vp, As, Bs);
    else       kv_body<false>(X, Wk, bk, Wv, bv, Kp, Vp, As, Bs);
}

// ---------------- K3: attention, one block per (b,h, 4-seed group) ---------
// QK pass rewritten for coalescing: per iteration a wave reads 8 K-rows x
// 128B contiguous (8 segments/instr instead of 64), dot reduced across the
// 8 d-chunk lanes via 3-step shfl_xor. PV pass already used this pattern.
#define QG 4
__global__ __launch_bounds__(256) void attn_kernel(
        const float* __restrict__ Qp, const u16* __restrict__ Kp,
        const u16* __restrict__ Vp, const int* __restrict__ pad,
        float* __restrict__ Oat) {
    __shared__ float qv[QG * DHX];          // 1 KB
    __shared__ float sc[QG * LX];           // 32 KB
    __shared__ float rpart[256 * 8];        // 8 KB
    __shared__ float invs[QG];
    const int blk = blockIdx.x;
    const int nqg = NSX / QG;               // 8
    const int b  = blk / (HX * nqg);
    const int h  = (blk / nqg) % HX;
    const int q0 = (blk % nqg) * QG;
    const int t = threadIdx.x;
    const int w = t >> 6, lane = t & 63;

    qv[t] = Qp[(size_t)(q0 + (t >> 6)) * DVX + h * DHX + (t & 63)];
    __syncthreads();

    const u16* Kb = Kp + (size_t)b * LX * DVX + h * DHX;
    const int rsub = lane >> 3;             // row within octet (0..7)
    const int dsub = lane & 7;              // d-chunk (0..7)
    float qc[8];
#pragma unroll
    for (int e = 0; e < 8; e++) qc[e] = qv[w * DHX + dsub * 8 + e];

    float lmax = -3e38f;
    for (int i = 0; i < LX / 8; i++) {
        int k = i * 8 + rsub;
        uint4 v = *(const uint4*)(Kb + (size_t)k * DVX + dsub * 8);
        float s = bfu(v.x & 0xffff) * qc[0] + bfu(v.x >> 16) * qc[1]
                + bfu(v.y & 0xffff) * qc[2] + bfu(v.y >> 16) * qc[3]
                + bfu(v.z & 0xffff) * qc[4] + bfu(v.z >> 16) * qc[5]
                + bfu(v.w & 0xffff) * qc[6] + bfu(v.w >> 16) * qc[7];
        s += __shfl_xor(s, 1, 64);
        s += __shfl_xor(s, 2, 64);
        s += __shfl_xor(s, 4, 64);
        s *= 0.03125f;
        s = (pad[b * LX + k] != 0) ? s : -1e30f;
        if (dsub == 0) sc[w * LX + k] = s;
        lmax = fmaxf(lmax, s);
    }
#pragma unroll
    for (int off = 32; off > 0; off >>= 1)
        lmax = fmaxf(lmax, __shfl_xor(lmax, off, 64));
    float lsum = 0.f;
    for (int i = 0; i < LX / 64; i++) {
        int k = i * 64 + lane;
        float sv = sc[w * LX + k];
        float e = (sv > -1e29f) ? __expf(sv - lmax) : 0.f;
        sc[w * LX + k] = e;
        lsum += e;
    }
#pragma unroll
    for (int off = 32; off > 0; off >>= 1)
        lsum += __shfl_xor(lsum, off, 64);
    if (lane == 0) invs[w] = (lsum > 0.f) ? 1.f / lsum : 0.f;

    const int kg = (t >> 3) & 7, dg = t & 7;
    const u16* Vb = Vp + (size_t)b * LX * DVX + h * DHX + dg * 8;
    float a8[8];
#pragma unroll
    for (int e = 0; e < 8; e++) a8[e] = 0.f;
    for (int i = 0; i < LX / 8; i++) {
        int k = i * 8 + kg;
        float p = sc[w * LX + k];
        uint4 v = *(const uint4*)(Vb + (size_t)k * DVX);
        a8[0] += p * bfu(v.x & 0xffff); a8[1] += p * bfu(v.x >> 16);
        a8[2] += p * bfu(v.y & 0xffff); a8[3] += p * bfu(v.y >> 16);
        a8[4] += p * bfu(v.z & 0xffff); a8[5] += p * bfu(v.z >> 16);
        a8[6] += p * bfu(v.w & 0xffff); a8[7] += p * bfu(v.w >> 16);
    }
#pragma unroll
    for (int e = 0; e < 8; e++) rpart[t * 8 + e] = a8[e];
    __syncthreads();

    {
        int q = t >> 6, d = t & 63;
        float o = 0.f;
#pragma unroll
        for (int g = 0; g < 8; g++)
            o += rpart[(q * 64 + g * 8 + (d >> 3)) * 8 + (d & 7)];
        o *= invs[q];
        Oat[((size_t)(b * NSX + q0 + q)) * DVX + h * DHX + d] = o;
    }
}

// ---------------- K4: residual + LN0 + MLP(relu) residual + LN1 ------------
template<bool ISF>
__device__ void epi_body(float* u, float* y0, float* red,
                         const float* __restrict__ Oat, const void* __restrict__ S,
                         const void* __restrict__ Wo, const void* __restrict__ bo,
                         const void* __restrict__ g0, const void* __restrict__ be0,
                         const void* __restrict__ g1, const void* __restrict__ be1,
                         void* __restrict__ out) {
    const int bq = blockIdx.x;            // (b*32+q)
    const int q = bq & 31;
    const int t = threadIdx.x;
    const int w = t >> 6, lane = t & 63;

    float ls = 0.f, ls2 = 0.f;
#pragma unroll
    for (int j = 0; j < 2; j++) {
        int c = t + 512 * j;
        float v = ld1(S, (size_t)q * DVX + c, ISF) + Oat[(size_t)bq * DVX + c];
        u[c] = v; ls += v; ls2 += v * v;
    }
    red[t] = ls; __syncthreads();
    for (int s2 = 256; s2 > 0; s2 >>= 1) { if (t < s2) red[t] += red[t + s2]; __syncthreads(); }
    float mu = red[0] / DVX; __syncthreads();
    red[t] = ls2; __syncthreads();
    for (int s2 = 256; s2 > 0; s2 >>= 1) { if (t < s2) red[t] += red[t + s2]; __syncthreads(); }
    float var = red[0] / DVX - mu * mu;
    float r = rsqrtf(var + EPSF);
    __syncthreads();
#pragma unroll
    for (int j = 0; j < 2; j++) {
        int c = t + 512 * j;
        y0[c] = (u[c] - mu) * r * ld1(g0, c, ISF) + ld1(be0, c, ISF);
    }
    __syncthreads();

    // GEMV: 8 waves x 128 iters = 1024 outputs.
    // y-slice per lane is loop-invariant -> hoist to registers (kills the
    // 32-way LDS bank conflict the in-loop y0 reads caused).
    float yr[16];
    if constexpr (ISF) {
#pragma unroll
        for (int e = 0; e < 16; e++) yr[e] = y0[lane * 16 + e];
    } else {
#pragma unroll
        for (int e = 0; e < 8; e++) { yr[e] = y0[lane * 8 + e]; yr[8 + e] = y0[512 + lane * 8 + e]; }
    }
    for (int i = 0; i < 128; i++) {
        int n = i * 8 + w;
        float p = 0.f;
        if constexpr (ISF) {
            float wv[8];
            const float* row = (const float*)Wo + (size_t)n * DVX;
            ld8<true>(row, lane * 16, wv);
#pragma unroll
            for (int e = 0; e < 8; e++) p += wv[e] * yr[e];
            ld8<true>(row, lane * 16 + 8, wv);
#pragma unroll
            for (int e = 0; e < 8; e++) p += wv[e] * yr[8 + e];
        } else {
            const uint4* row = (const uint4*)((const u16*)Wo + (size_t)n * DVX);
            uint4 v0 = row[lane], v1 = row[lane + 64];
            p += bfu(v0.x & 0xffff) * yr[0] + bfu(v0.x >> 16) * yr[1]
               + bfu(v0.y & 0xffff) * yr[2] + bfu(v0.y >> 16) * yr[3]
               + bfu(v0.z & 0xffff) * yr[4] + bfu(v0.z >> 16) * yr[5]
               + bfu(v0.w & 0xffff) * yr[6] + bfu(v0.w >> 16) * yr[7];
            p += bfu(v1.x & 0xffff) * yr[8]  + bfu(v1.x >> 16) * yr[9]
               + bfu(v1.y & 0xffff) * yr[10] + bfu(v1.y >> 16) * yr[11]
               + bfu(v1.z & 0xffff) * yr[12] + bfu(v1.z >> 16) * yr[13]
               + bfu(v1.w & 0xffff) * yr[14] + bfu(v1.w >> 16) * yr[15];
        }
#pragma unroll
        for (int off = 32; off > 0; off >>= 1)
            p += __shfl_xor(p, off, 64);
        if (lane == 0) {
            float z = p + ld1(bo, n, ISF);
            u[n] = y0[n] + fmaxf(z, 0.f);     // reuse u as y1
        }
    }
    __syncthreads();
    ls = 0.f; ls2 = 0.f;
#pragma unroll
    for (int j = 0; j < 2; j++) {
        int c = t + 512 * j; float v = u[c]; ls += v; ls2 += v * v;
    }
    red[t] = ls; __syncthreads();
    for (int s2 = 256; s2 > 0; s2 >>= 1) { if (t < s2) red[t] += red[t + s2]; __syncthreads(); }
    mu = red[0] / DVX; __syncthreads();
    red[t] = ls2; __syncthreads();
    for (int s2 = 256; s2 > 0; s2 >>= 1) { if (t < s2) red[t] += red[t + s2]; __syncthreads(); }
    var = red[0] / DVX - mu * mu;
    r = rsqrtf(var + EPSF);
#pragma unroll
    for (int j = 0; j < 2; j++) {
        int c = t + 512 * j;
        float v = (u[c] - mu) * r * ld1(g1, c, ISF) + ld1(be1, c, ISF);
        if (ISF) ((float*)out)[(size_t)bq * DVX + c] = v;
        else     ((u16*)out)[(size_t)bq * DVX + c] = f2b(v);
    }
}

__global__ __launch_bounds__(512) void epi_kernel(
        const int* __restrict__ flag,
        const float* __restrict__ Oat, const void* __restrict__ S,
        const void* __restrict__ Wo, const void* __restrict__ bo,
        const void* __restrict__ g0, const void* __restrict__ be0,
        const void* __restrict__ g1, const void* __restrict__ be1,
        void* __restrict__ out) {
    __shared__ float u[DVX];
    __shared__ float y0[DVX];
    __shared__ float red[512];
    if (*flag) epi_body<true>(u, y0, red, Oat, S, Wo, bo, g0, be0, g1, be1, out);
    else       epi_body<false>(u, y0, red, Oat, S, Wo, bo, g0, be0, g1, be1, out);
}

extern "C" void kernel_launch(void* const* d_in, const int* in_sizes, int n_in,
                              void* d_out, int out_size, void* d_ws, size_t ws_size,
                              hipStream_t stream) {
    (void)in_sizes; (void)n_in; (void)out_size;
    const void* X    = d_in[0];
    const int* pad   = (const int*)d_in[1];
    const void* S    = d_in[2];
    const void* Wq   = d_in[3];
    const void* bq   = d_in[4];
    const void* Wk   = d_in[5];
    const void* bk   = d_in[6];
    const void* Wv   = d_in[7];
    const void* bv   = d_in[8];
    const void* Wo   = d_in[9];
    const void* bo   = d_in[10];
    const void* g0   = d_in[11];
    const void* be0  = d_in[12];
    const void* g1   = d_in[13];
    const void* be1  = d_in[14];

    char* ws = (char*)d_ws;
    int*   flag = (int*)ws;                                // 256 B reserved
    float* Qp  = (float*)(ws + 256);                       // 128 KiB
    float* Oat = (float*)(ws + 256 + 131072);              // 1 MiB
    u16*   Kp  = (u16*)(ws + 256 + 131072 + 1048576);      // 32 MiB
    u16*   Vp  = Kp + (size_t)BX * LX * DVX;               // 32 MiB
    u16*   Xb  = Vp + (size_t)BX * LX * DVX;               // 128 MiB (bf16 X)
    u16*   Wkb = Xb + (size_t)BX * LX * DIMX;              // 8 MiB
    u16*   Wvb = Wkb + (size_t)DVX * DIMX;                 // 8 MiB

    size_t need = 256 + 131072 + 1048576
                + 2 * (size_t)BX * LX * DVX * 2
                + (size_t)BX * LX * DIMX * 2
                + 2 * (size_t)DVX * DIMX * 2;              // ~209 MiB

    detect_kernel<<<1, 256, 0, stream>>>((const u16*)X, flag);
    qp_kernel<<<8192, 256, 0, stream>>>(flag, S, Wq, bq, Qp);

    if (ws_size >= need) {
        cvt_kernel<<<2048, 256, 0, stream>>>(flag, (const float*)X, Xb,
                                             BX * LX * DIMX / 8);
        cvt_kernel<<<512, 256, 0, stream>>>(flag, (const float*)Wk, Wkb,
                                            DVX * DIMX / 8);
        cvt_kernel<<<512, 256, 0, stream>>>(flag, (const float*)Wv, Wvb,
                                            DVX * DIMX / 8);
        kv_gemm2<<<2048, 256, 0, stream>>>(flag, X, Xb, Wk, bk, Wv, bv,
                                           Wkb, Wvb, Kp, Vp);
    } else {
        kv_gemm<<<2048, 256, 0, stream>>>(flag, X, Wk, bk, Wv, bv, Kp, Vp);
    }

    attn_kernel<<<BX * HX * (NSX / QG), 256, 0, stream>>>(Qp, Kp, Vp, pad, Oat);
    epi_kernel<<<BX * NSX, 512, 0, stream>>>(flag, Oat, S, Wo, bo, g0, be0, g1, be1, (void*)d_out);
}

// Round 3
// 1119.565 us; speedup vs baseline: 1.0699x; 1.0699x over previous
//
#include <hip/hip_runtime.h>

#define DIMX 4096
#define DVX  1024
#define HX   16
#define DHX  64
#define NSX  32
#define BX   8
#define LX   2048
#define EPSF 1e-5f

typedef unsigned short u16;
typedef unsigned int   u32;

using bf16x8 = __attribute__((ext_vector_type(8))) __bf16;
using f32x4  = __attribute__((ext_vector_type(4))) float;

__device__ __forceinline__ float bfu(u16 u) {
    union { u32 i; float f; } c; c.i = ((u32)u) << 16; return c.f;
}
__device__ __forceinline__ u16 f2b(float f) {
    union { float f; u32 u; } c; c.f = f;
    u32 u = c.u;
    u32 r = (u + 0x7fffu + ((u >> 16) & 1u)) >> 16;
    return (u16)r;
}

// async global->LDS DMA, 16B per lane; LDS dest = wave-uniform base + lane*16
__device__ __forceinline__ void async16(const u16* g, u16* l) {
    __builtin_amdgcn_global_load_lds(
        (const __attribute__((address_space(1))) void*)g,
        (__attribute__((address_space(3))) void*)l, 16, 0, 0);
}

// load 8 logical elements (idx multiple of 8, 16B-aligned base) as fp32
template<bool ISF>
__device__ __forceinline__ void ld8(const void* base, size_t idx, float o[8]) {
    if (ISF) {
        const float* f = (const float*)base + idx;
        float4 a = *(const float4*)f, b = *(const float4*)(f + 4);
        o[0]=a.x; o[1]=a.y; o[2]=a.z; o[3]=a.w;
        o[4]=b.x; o[5]=b.y; o[6]=b.z; o[7]=b.w;
    } else {
        const u16* h = (const u16*)base + idx;
        uint4 v = *(const uint4*)h;
        o[0]=bfu(v.x & 0xffff); o[1]=bfu(v.x >> 16);
        o[2]=bfu(v.y & 0xffff); o[3]=bfu(v.y >> 16);
        o[4]=bfu(v.z & 0xffff); o[5]=bfu(v.z >> 16);
        o[6]=bfu(v.w & 0xffff); o[7]=bfu(v.w >> 16);
    }
}
__device__ __forceinline__ float ld1(const void* base, size_t idx, bool isf) {
    return isf ? ((const float*)base)[idx] : bfu(((const u16*)base)[idx]);
}

// ---------------- K0: dtype detector -------------------------------------
__global__ __launch_bounds__(256) void detect_kernel(const u16* __restrict__ X,
                                                     int* __restrict__ flag) {
    __shared__ int cnt;
    if (threadIdx.x == 0) cnt = 0;
    __syncthreads();
    int local = 0;
    for (int i = threadIdx.x; i < 8192; i += 256) {
        u32 e = ((u32)X[i] >> 7) & 0xffu;
        if (e >= 200u) local++;
    }
    atomicAdd(&cnt, local);
    __syncthreads();
    if (threadIdx.x == 0) *flag = (cnt > 32) ? 1 : 0;
}

// ---------------- K0b: fp32 -> bf16 bulk converter -------------------------
__global__ __launch_bounds__(256) void cvt_kernel(const int* __restrict__ flag,
                                                  const float* __restrict__ src,
                                                  u16* __restrict__ dst, int ngrp) {
    if (*flag == 0) return;
    int stride = gridDim.x * 256;
    for (int i = blockIdx.x * 256 + threadIdx.x; i < ngrp; i += stride) {
        const float4* f = (const float4*)(src + (size_t)i * 8);
        float4 a = f[0], b = f[1];
        uint4 r;
        r.x = (u32)f2b(a.x) | ((u32)f2b(a.y) << 16);
        r.y = (u32)f2b(a.z) | ((u32)f2b(a.w) << 16);
        r.z = (u32)f2b(b.x) | ((u32)f2b(b.y) << 16);
        r.w = (u32)f2b(b.z) | ((u32)f2b(b.w) << 16);
        *(uint4*)(dst + (size_t)i * 8) = r;
    }
}

// ---------------- K1: Qp = S @ Wq^T + bq  -- wave-per-output GEMV ----------
__global__ __launch_bounds__(256) void qp_kernel(
        const int* __restrict__ flag, const void* __restrict__ S,
        const void* __restrict__ Wq, const void* __restrict__ bq,
        float* __restrict__ Qp) {
    int wid = blockIdx.x * 4 + (threadIdx.x >> 6);   // 0..32767
    int lane = threadIdx.x & 63;
    int q = wid >> 10, n = wid & 1023;
    bool isf = (*flag != 0);
    float p = 0.f;
    if (isf) {
        const float* srow = (const float*)S + (size_t)q * DVX + lane * 16;
        const float* wrow = (const float*)Wq + (size_t)n * DVX + lane * 16;
#pragma unroll
        for (int e = 0; e < 16; e += 4) {
            float4 a = *(const float4*)(srow + e);
            float4 b = *(const float4*)(wrow + e);
            p += a.x * b.x + a.y * b.y + a.z * b.z + a.w * b.w;
        }
    } else {
        const u16* srow = (const u16*)S + (size_t)q * DVX + lane * 16;
        const u16* wrow = (const u16*)Wq + (size_t)n * DVX + lane * 16;
#pragma unroll
        for (int c = 0; c < 2; c++) {
            uint4 a = *(const uint4*)(srow + c * 8);
            uint4 b = *(const uint4*)(wrow + c * 8);
            p += bfu(a.x & 0xffff) * bfu(b.x & 0xffff) + bfu(a.x >> 16) * bfu(b.x >> 16)
               + bfu(a.y & 0xffff) * bfu(b.y & 0xffff) + bfu(a.y >> 16) * bfu(b.y >> 16)
               + bfu(a.z & 0xffff) * bfu(b.z & 0xffff) + bfu(a.z >> 16) * bfu(b.z >> 16)
               + bfu(a.w & 0xffff) * bfu(b.w & 0xffff) + bfu(a.w >> 16) * bfu(b.w >> 16);
        }
    }
#pragma unroll
    for (int off = 32; off > 0; off >>= 1)
        p += __shfl_xor(p, off, 64);
    if (lane == 0) Qp[wid] = p + ld1(bq, n, isf);
}

// ---------------- K2a: 256x256 BK=64 phase-pipelined GEMM (T2+T3+T4+T5) ----
// 512 threads = 8 waves (2 M x 4 N), per-wave C = 128x64.
// LDS: A[2][256][64] + B[2][256][64] bf16 = 128 KiB dynamic, double-buffered.
// Chunk swizzle: LDS 16B-chunk c of row r holds global chunk c^(r&7)
//   -> ds_read_b128 frag reads conflict-free per 8-lane group (same family
//      as the verified kv_gemm2 swizzle, extended to 8 chunks).
// Schedule per K-tile: phase0 {12 ds_read (B all + A m0,m1) + ALL 8 DMA
// issues for kt+1 + 16 MFMA}; phases 1-3 {4 ds_read + 16 MFMA}; boundary
// {sched_barrier, vmcnt(0) (issued ~64 MFMA earlier -> near-free), barrier}.
__global__ __launch_bounds__(512, 2) void kv_gemm3(
        const int* __restrict__ flag,
        const void* __restrict__ X,  const u16* __restrict__ Xb,
        const void* __restrict__ Wk, const void* __restrict__ bk,
        const void* __restrict__ Wv, const void* __restrict__ bv,
        const u16* __restrict__ Wkb, const u16* __restrict__ Wvb,
        u16* __restrict__ Kp, u16* __restrict__ Vp) {
    extern __shared__ __align__(16) u16 lds[];   // 65536 elems = 128 KiB
    const bool isf = (*flag != 0);
    const u16* Xs = isf ? Xb : (const u16*)X;

    const int t = threadIdx.x;
    const int lane = t & 63, w = t >> 6;
    const int wm = w >> 2, wn = w & 3;
    const int quad = lane >> 4, l16 = lane & 15;
    const int l8 = l16 & 7;

    // XCD-aware swizzle over 512 blocks (512 % 8 == 0)
    const int bid = blockIdx.x;
    const int swz = (bid & 7) * 64 + (bid >> 3);
    const int mt = swz >> 3, nt = swz & 7;
    const int m0 = mt * 256, n0 = nt * 256;

    const u16* Wb16; const void* bias; int boff;
    if (n0 < DVX) { Wb16 = (isf ? Wkb : (const u16*)Wk) + (size_t)n0 * DIMX;
                    bias = bk; boff = n0; }
    else          { Wb16 = (isf ? Wvb : (const u16*)Wv) + (size_t)(n0 - DVX) * DIMX;
                    bias = bv; boff = n0 - DVX; }

    f32x4 acc[8][4];
#pragma unroll
    for (int i = 0; i < 8; i++)
#pragma unroll
        for (int j = 0; j < 4; j++) acc[i][j] = {0.f, 0.f, 0.f, 0.f};

    // --- prologue: stage tile 0 into buffer 0 ---
    {
        u16* An = lds;
        u16* Bn = lds + 32768;
#pragma unroll
        for (int i = 0; i < 4; i++) {
            int gi = i * 512 + t;
            int r = gi >> 3;
            int g = (gi & 7) ^ (r & 7);
            async16(Xs + (size_t)(m0 + r) * DIMX + g * 8, An + gi * 8);
        }
#pragma unroll
        for (int i = 0; i < 4; i++) {
            int gi = i * 512 + t;
            int r = gi >> 3;
            int g = (gi & 7) ^ (r & 7);
            async16(Wb16 + (size_t)r * DIMX + g * 8, Bn + gi * 8);
        }
        asm volatile("s_waitcnt vmcnt(0)" ::: "memory");
        __builtin_amdgcn_s_barrier();
    }

    for (int kt = 0; kt < DIMX / 64; kt++) {
        u16* Ab = lds + (kt & 1) * 16384;
        u16* Bb = lds + 32768 + (kt & 1) * 16384;
        u16* An = lds + ((kt + 1) & 1) * 16384;
        u16* Bn = lds + 32768 + ((kt + 1) & 1) * 16384;
        const int k1 = (kt + 1) * 64;
        const bool st = (kt + 1) < (DIMX / 64);

        // ---- phase 0: B all + A(m0,m1), stage issues, MFMA quadrant 0 ----
        bf16x8 bfr[4][2];
#pragma unroll
        for (int ni = 0; ni < 4; ni++)
#pragma unroll
            for (int ks = 0; ks < 2; ks++) {
                int R = wn * 64 + ni * 16 + l16;
                int cc = ((ks * 4 + quad) ^ l8);
                bfr[ni][ks] = *(const bf16x8*)&Bb[R * 64 + cc * 8];
            }
        {
            bf16x8 a[2][2];
#pragma unroll
            for (int dm = 0; dm < 2; dm++)
#pragma unroll
                for (int ks = 0; ks < 2; ks++) {
                    int R = wm * 128 + dm * 16 + l16;
                    int cc = ((ks * 4 + quad) ^ l8);
                    a[dm][ks] = *(const bf16x8*)&Ab[R * 64 + cc * 8];
                }
            if (st) {
#pragma unroll
                for (int i = 0; i < 4; i++) {
                    int gi = i * 512 + t;
                    int r = gi >> 3;
                    int g = (gi & 7) ^ (r & 7);
                    async16(Xs + (size_t)(m0 + r) * DIMX + k1 + g * 8, An + gi * 8);
                }
#pragma unroll
                for (int i = 0; i < 4; i++) {
                    int gi = i * 512 + t;
                    int r = gi >> 3;
                    int g = (gi & 7) ^ (r & 7);
                    async16(Wb16 + (size_t)r * DIMX + k1 + g * 8, Bn + gi * 8);
                }
            }
            __builtin_amdgcn_s_setprio(1);
#pragma unroll
            for (int dm = 0; dm < 2; dm++)
#pragma unroll
                for (int ni = 0; ni < 4; ni++)
#pragma unroll
                    for (int ks = 0; ks < 2; ks++)
                        acc[dm][ni] = __builtin_amdgcn_mfma_f32_16x16x32_bf16(
                            a[dm][ks], bfr[ni][ks], acc[dm][ni], 0, 0, 0);
            __builtin_amdgcn_s_setprio(0);
        }
        __builtin_amdgcn_s_barrier();

        // ---- phases 1..3: A(m2p,m2p+1) + MFMA quadrant p ----
#pragma unroll
        for (int p = 1; p < 4; p++) {
            bf16x8 a[2][2];
#pragma unroll
            for (int dm = 0; dm < 2; dm++)
#pragma unroll
                for (int ks = 0; ks < 2; ks++) {
                    int R = wm * 128 + (2 * p + dm) * 16 + l16;
                    int cc = ((ks * 4 + quad) ^ l8);
                    a[dm][ks] = *(const bf16x8*)&Ab[R * 64 + cc * 8];
                }
            __builtin_amdgcn_s_setprio(1);
#pragma unroll
            for (int dm = 0; dm < 2; dm++)
#pragma unroll
                for (int ni = 0; ni < 4; ni++)
#pragma unroll
                    for (int ks = 0; ks < 2; ks++)
                        acc[2 * p + dm][ni] = __builtin_amdgcn_mfma_f32_16x16x32_bf16(
                            a[dm][ks], bfr[ni][ks], acc[2 * p + dm][ni], 0, 0, 0);
            __builtin_amdgcn_s_setprio(0);
            if (p < 3) __builtin_amdgcn_s_barrier();
        }

        // ---- tile boundary: next buffer must be fully landed ----
        __builtin_amdgcn_sched_barrier(0);
        asm volatile("s_waitcnt vmcnt(0)" ::: "memory");
        __builtin_amdgcn_s_barrier();
        __builtin_amdgcn_sched_barrier(0);
    }

    // ---- epilogue: D layout col = lane&15, row = quad*4+reg ----
    float bb[4];
#pragma unroll
    for (int ni = 0; ni < 4; ni++)
        bb[ni] = ld1(bias, (size_t)(boff + wn * 64 + ni * 16 + l16), isf);
#pragma unroll
    for (int mi = 0; mi < 8; mi++) {
#pragma unroll
        for (int ni = 0; ni < 4; ni++) {
            int colL = wn * 64 + ni * 16 + l16;
            int col = n0 + colL;
            u16* dst; int dcol;
            if (col < DVX) { dst = Kp; dcol = col; }
            else           { dst = Vp; dcol = col - DVX; }
#pragma unroll
            for (int r = 0; r < 4; r++) {
                int row = m0 + wm * 128 + mi * 16 + quad * 4 + r;
                dst[(size_t)row * DVX + dcol] = f2b(acc[mi][ni][r] + bb[ni]);
            }
        }
    }
}

// ---------------- K2b: 128x128 m97-structure GEMM (fallback fast path) -----
#define TM 128
#define TN 128
#define BKK 32
#define LDT 32

__device__ __forceinline__ uint4 pack8(float o[8]) {
    uint4 r;
    r.x = (u32)f2b(o[0]) | ((u32)f2b(o[1]) << 16);
    r.y = (u32)f2b(o[2]) | ((u32)f2b(o[3]) << 16);
    r.z = (u32)f2b(o[4]) | ((u32)f2b(o[5]) << 16);
    r.w = (u32)f2b(o[6]) | ((u32)f2b(o[7]) << 16);
    return r;
}

__global__ __launch_bounds__(256) void kv_gemm2(
        const int* __restrict__ flag,
        const void* __restrict__ X,  const u16* __restrict__ Xb,
        const void* __restrict__ Wk, const void* __restrict__ bk,
        const void* __restrict__ Wv, const void* __restrict__ bv,
        const u16* __restrict__ Wkb, const u16* __restrict__ Wvb,
        u16* __restrict__ Kp, u16* __restrict__ Vp) {
    __shared__ u16 As[TM * LDT];
    __shared__ u16 Bs[TN * LDT];
    const bool isf = (*flag != 0);
    const u16* Xs = isf ? Xb : (const u16*)X;

    const int t = threadIdx.x;
    const int lane = t & 63, w = t >> 6;
    const int wm = w >> 1, wn = w & 1;
    const int quad = lane >> 4, l16 = lane & 15;
    const int bl = blockIdx.x;
    const int xcd = bl & 7, bq = bl >> 3;
    const int m0 = (xcd + 8 * (bq >> 4)) * TM;
    const int n0 = (bq & 15) * TN;
    const u16* Wb16; const void* bias; int boff;
    if (n0 < DVX) { Wb16 = (isf ? Wkb : (const u16*)Wk) + (size_t)n0 * DIMX;
                    bias = bk; boff = n0; }
    else          { Wb16 = (isf ? Wvb : (const u16*)Wv) + (size_t)(n0 - DVX) * DIMX;
                    bias = bv; boff = n0 - DVX; }

    f32x4 acc[4][4];
#pragma unroll
    for (int i = 0; i < 4; i++)
#pragma unroll
        for (int j = 0; j < 4; j++) acc[i][j] = {0.f, 0.f, 0.f, 0.f};

    const int srow = lane >> 2;
    const int gcol = ((lane & 3) ^ ((lane >> 3) & 3)) * 8;
    const int ph = (l16 >> 1) & 3;

    for (int k0 = 0; k0 < DIMX; k0 += BKK) {
        __syncthreads();
#pragma unroll
        for (int c = 0; c < 2; c++) {
            int rr = w * 32 + c * 16;
            async16(Xs + (size_t)(m0 + rr + srow) * DIMX + k0 + gcol,
                    As + rr * LDT);
            async16(Wb16 + (size_t)(rr + srow) * DIMX + k0 + gcol,
                    Bs + rr * LDT);
        }
        __syncthreads();
        bf16x8 af[4], bfr[4];
#pragma unroll
        for (int mi = 0; mi < 4; mi++) {
            int ar = wm * 64 + mi * 16 + l16;
            af[mi] = *(const bf16x8*)&As[ar * LDT + (quad ^ ph) * 8];
        }
#pragma unroll
        for (int ni = 0; ni < 4; ni++) {
            int br = wn * 64 + ni * 16 + l16;
            bfr[ni] = *(const bf16x8*)&Bs[br * LDT + (quad ^ ph) * 8];
        }
#pragma unroll
        for (int mi = 0; mi < 4; mi++)
#pragma unroll
            for (int ni = 0; ni < 4; ni++)
                acc[mi][ni] = __builtin_amdgcn_mfma_f32_16x16x32_bf16(
                    af[mi], bfr[ni], acc[mi][ni], 0, 0, 0);
    }

#pragma unroll
    for (int mi = 0; mi < 4; mi++) {
#pragma unroll
        for (int ni = 0; ni < 4; ni++) {
            int colL = wn * 64 + ni * 16 + l16;
            int col = n0 + colL;
            float bb = ld1(bias, (size_t)(boff + colL), isf);
            u16* dst; int dcol;
            if (col < DVX) { dst = Kp; dcol = col; }
            else           { dst = Vp; dcol = col - DVX; }
#pragma unroll
            for (int r = 0; r < 4; r++) {
                int row = m0 + wm * 64 + mi * 16 + quad * 4 + r;
                dst[(size_t)row * DVX + dcol] = f2b(acc[mi][ni][r] + bb);
            }
        }
    }
}

// -------- fallback path (small workspace): original dual-dtype body --------
template<bool ISF>
__device__ void kv_body(const void* __restrict__ X,
                        const void* __restrict__ Wk, const void* __restrict__ bk,
                        const void* __restrict__ Wv, const void* __restrict__ bv,
                        u16* __restrict__ Kp, u16* __restrict__ Vp,
                        u16* As, u16* Bs) {
    const int t = threadIdx.x;
    const int lane = t & 63, w = t >> 6;
    const int wm = w >> 1, wn = w & 1;
    const int quad = lane >> 4, l16 = lane & 15;
    const int bl = blockIdx.x;
    const int xcd = bl & 7, bq = bl >> 3;
    const int m0 = (xcd + 8 * (bq >> 4)) * TM;
    const int n0 = (bq & 15) * TN;
    const void* Wbase; const void* bias; int boff;
    size_t woff;
    if (n0 < DVX) { Wbase = Wk; bias = bk; woff = (size_t)n0 * DIMX; boff = n0; }
    else          { Wbase = Wv; bias = bv; woff = (size_t)(n0 - DVX) * DIMX; boff = n0 - DVX; }
    const u16* Wb16 = (const u16*)Wbase + woff;
    const float* Wbf = (const float*)Wbase + woff;

    f32x4 acc[4][4];
#pragma unroll
    for (int i = 0; i < 4; i++)
#pragma unroll
        for (int j = 0; j < 4; j++) acc[i][j] = {0.f, 0.f, 0.f, 0.f};

    const int srow = lane >> 2;
    const int gcol = ((lane & 3) ^ ((lane >> 3) & 3)) * 8;
    const int ph = (l16 >> 1) & 3;
    const int r0 = t >> 2, c0 = (t & 3) * 8;
    const int r1 = r0 + 64;
    const int swc = (((t & 3) ^ ((r0 >> 1) & 3))) * 8;

    for (int k0 = 0; k0 < DIMX; k0 += BKK) {
        if constexpr (ISF) {
            float oa0[8], oa1[8], ob0[8], ob1[8];
            ld8<true>(X,   (size_t)(m0 + r0) * DIMX + k0 + c0, oa0);
            ld8<true>(X,   (size_t)(m0 + r1) * DIMX + k0 + c0, oa1);
            ld8<true>(Wbf, (size_t)r0 * DIMX + k0 + c0, ob0);
            ld8<true>(Wbf, (size_t)r1 * DIMX + k0 + c0, ob1);
            __syncthreads();
            *(uint4*)&As[r0 * LDT + swc] = pack8(oa0);
            *(uint4*)&As[r1 * LDT + swc] = pack8(oa1);
            *(uint4*)&Bs[r0 * LDT + swc] = pack8(ob0);
            *(uint4*)&Bs[r1 * LDT + swc] = pack8(ob1);
        } else {
            __syncthreads();
#pragma unroll
            for (int c = 0; c < 2; c++) {
                int rr = w * 32 + c * 16;
                async16((const u16*)X + (size_t)(m0 + rr + srow) * DIMX + k0 + gcol,
                        As + rr * LDT);
                async16(Wb16 + (size_t)(rr + srow) * DIMX + k0 + gcol,
                        Bs + rr * LDT);
            }
        }
        __syncthreads();
        bf16x8 af[4], bfr[4];
#pragma unroll
        for (int mi = 0; mi < 4; mi++) {
            int ar = wm * 64 + mi * 16 + l16;
            af[mi] = *(const bf16x8*)&As[ar * LDT + (quad ^ ph) * 8];
        }
#pragma unroll
        for (int ni = 0; ni < 4; ni++) {
            int br = wn * 64 + ni * 16 + l16;
            bfr[ni] = *(const bf16x8*)&Bs[br * LDT + (quad ^ ph) * 8];
        }
#pragma unroll
        for (int mi = 0; mi < 4; mi++)
#pragma unroll
            for (int ni = 0; ni < 4; ni++)
                acc[mi][ni] = __builtin_amdgcn_mfma_f32_16x16x32_bf16(
                    af[mi], bfr[ni], acc[mi][ni], 0, 0, 0);
    }

#pragma unroll
    for (int mi = 0; mi < 4; mi++) {
#pragma unroll
        for (int ni = 0; ni < 4; ni++) {
            int colL = wn * 64 + ni * 16 + l16;
            int col = n0 + colL;
            float bb = ld1(bias, (size_t)(boff + colL), ISF);
            u16* dst; int dcol;
            if (col < DVX) { dst = Kp; dcol = col; }
            else           { dst = Vp; dcol = col - DVX; }
#pragma unroll
            for (int r = 0; r < 4; r++) {
                int row = m0 + wm * 64 + mi * 16 + quad * 4 + r;
                dst[(size_t)row * DVX + dcol] = f2b(acc[mi][ni][r] + bb);
            }
        }
    }
}

__global__ __launch_bounds__(256) void kv_gemm(
        const int* __restrict__ flag, const void* __restrict__ X,
        const void* __restrict__ Wk, const void* __restrict__ bk,
        const void* __restrict__ Wv, const void* __restrict__ bv,
        u16* __restrict__ Kp, u16* __restrict__ Vp) {
    __shared__ u16 As[TM * LDT];
    __shared__ u16 Bs[TN * LDT];
    if (*flag) kv_body<true>(X, Wk, bk, Wv, bv, Kp, Vp, As, Bs);
    else       kv_body<false>(X, Wk, bk, Wv, bv, Kp, Vp, As, Bs);
}

// ---------------- K3: attention, one block per (b,h, 4-seed group) ---------
#define QG 4
__global__ __launch_bounds__(256) void attn_kernel(
        const float* __restrict__ Qp, const u16* __restrict__ Kp,
        const u16* __restrict__ Vp, const int* __restrict__ pad,
        float* __restrict__ Oat) {
    __shared__ float qv[QG * DHX];          // 1 KB
    __shared__ float sc[QG * LX];           // 32 KB
    __shared__ float rpart[256 * 8];        // 8 KB
    __shared__ float invs[QG];
    const int blk = blockIdx.x;
    const int nqg = NSX / QG;               // 8
    const int b  = blk / (HX * nqg);
    const int h  = (blk / nqg) % HX;
    const int q0 = (blk % nqg) * QG;
    const int t = threadIdx.x;
    const int w = t >> 6, lane = t & 63;

    qv[t] = Qp[(size_t)(q0 + (t >> 6)) * DVX + h * DHX + (t & 63)];
    __syncthreads();

    const u16* Kb = Kp + (size_t)b * LX * DVX + h * DHX;
    const int rsub = lane >> 3;             // row within octet (0..7)
    const int dsub = lane & 7;              // d-chunk (0..7)
    float qc[8];
#pragma unroll
    for (int e = 0; e < 8; e++) qc[e] = qv[w * DHX + dsub * 8 + e];

    float lmax = -3e38f;
    for (int i = 0; i < LX / 8; i++) {
        int k = i * 8 + rsub;
        uint4 v = *(const uint4*)(Kb + (size_t)k * DVX + dsub * 8);
        float s = bfu(v.x & 0xffff) * qc[0] + bfu(v.x >> 16) * qc[1]
                + bfu(v.y & 0xffff) * qc[2] + bfu(v.y >> 16) * qc[3]
                + bfu(v.z & 0xffff) * qc[4] + bfu(v.z >> 16) * qc[5]
                + bfu(v.w & 0xffff) * qc[6] + bfu(v.w >> 16) * qc[7];
        s += __shfl_xor(s, 1, 64);
        s += __shfl_xor(s, 2, 64);
        s += __shfl_xor(s, 4, 64);
        s *= 0.03125f;
        s = (pad[b * LX + k] != 0) ? s : -1e30f;
        if (dsub == 0) sc[w * LX + k] = s;
        lmax = fmaxf(lmax, s);
    }
#pragma unroll
    for (int off = 32; off > 0; off >>= 1)
        lmax = fmaxf(lmax, __shfl_xor(lmax, off, 64));
    float lsum = 0.f;
    for (int i = 0; i < LX / 64; i++) {
        int k = i * 64 + lane;
        float sv = sc[w * LX + k];
        float e = (sv > -1e29f) ? __expf(sv - lmax) : 0.f;
        sc[w * LX + k] = e;
        lsum += e;
    }
#pragma unroll
    for (int off = 32; off > 0; off >>= 1)
        lsum += __shfl_xor(lsum, off, 64);
    if (lane == 0) invs[w] = (lsum > 0.f) ? 1.f / lsum : 0.f;

    const int kg = (t >> 3) & 7, dg = t & 7;
    const u16* Vb = Vp + (size_t)b * LX * DVX + h * DHX + dg * 8;
    float a8[8];
#pragma unroll
    for (int e = 0; e < 8; e++) a8[e] = 0.f;
    for (int i = 0; i < LX / 8; i++) {
        int k = i * 8 + kg;
        float p = sc[w * LX + k];
        uint4 v = *(const uint4*)(Vb + (size_t)k * DVX);
        a8[0] += p * bfu(v.x & 0xffff); a8[1] += p * bfu(v.x >> 16);
        a8[2] += p * bfu(v.y & 0xffff); a8[3] += p * bfu(v.y >> 16);
        a8[4] += p * bfu(v.z & 0xffff); a8[5] += p * bfu(v.z >> 16);
        a8[6] += p * bfu(v.w & 0xffff); a8[7] += p * bfu(v.w >> 16);
    }
#pragma unroll
    for (int e = 0; e < 8; e++) rpart[t * 8 + e] = a8[e];
    __syncthreads();

    {
        int q = t >> 6, d = t & 63;
        float o = 0.f;
#pragma unroll
        for (int g = 0; g < 8; g++)
            o += rpart[(q * 64 + g * 8 + (d >> 3)) * 8 + (d & 7)];
        o *= invs[q];
        Oat[((size_t)(b * NSX + q0 + q)) * DVX + h * DHX + d] = o;
    }
}

// ---------------- K4: residual + LN0 + MLP(relu) residual + LN1 ------------
template<bool ISF>
__device__ void epi_body(float* u, float* y0, float* red,
                         const float* __restrict__ Oat, const void* __restrict__ S,
                         const void* __restrict__ Wo, const void* __restrict__ bo,
                         const void* __restrict__ g0, const void* __restrict__ be0,
                         const void* __restrict__ g1, const void* __restrict__ be1,
                         void* __restrict__ out) {
    const int bq = blockIdx.x;            // (b*32+q)
    const int q = bq & 31;
    const int t = threadIdx.x;
    const int w = t >> 6, lane = t & 63;

    float ls = 0.f, ls2 = 0.f;
#pragma unroll
    for (int j = 0; j < 2; j++) {
        int c = t + 512 * j;
        float v = ld1(S, (size_t)q * DVX + c, ISF) + Oat[(size_t)bq * DVX + c];
        u[c] = v; ls += v; ls2 += v * v;
    }
    red[t] = ls; __syncthreads();
    for (int s2 = 256; s2 > 0; s2 >>= 1) { if (t < s2) red[t] += red[t + s2]; __syncthreads(); }
    float mu = red[0] / DVX; __syncthreads();
    red[t] = ls2; __syncthreads();
    for (int s2 = 256; s2 > 0; s2 >>= 1) { if (t < s2) red[t] += red[t + s2]; __syncthreads(); }
    float var = red[0] / DVX - mu * mu;
    float r = rsqrtf(var + EPSF);
    __syncthreads();
#pragma unroll
    for (int j = 0; j < 2; j++) {
        int c = t + 512 * j;
        y0[c] = (u[c] - mu) * r * ld1(g0, c, ISF) + ld1(be0, c, ISF);
    }
    __syncthreads();

    float yr[16];
    if constexpr (ISF) {
#pragma unroll
        for (int e = 0; e < 16; e++) yr[e] = y0[lane * 16 + e];
    } else {
#pragma unroll
        for (int e = 0; e < 8; e++) { yr[e] = y0[lane * 8 + e]; yr[8 + e] = y0[512 + lane * 8 + e]; }
    }
    for (int i = 0; i < 128; i++) {
        int n = i * 8 + w;
        float p = 0.f;
        if constexpr (ISF) {
            float wv[8];
            const float* row = (const float*)Wo + (size_t)n * DVX;
            ld8<true>(row, lane * 16, wv);
#pragma unroll
            for (int e = 0; e < 8; e++) p += wv[e] * yr[e];
            ld8<true>(row, lane * 16 + 8, wv);
#pragma unroll
            for (int e = 0; e < 8; e++) p += wv[e] * yr[8 + e];
        } else {
            const uint4* row = (const uint4*)((const u16*)Wo + (size_t)n * DVX);
            uint4 v0 = row[lane], v1 = row[lane + 64];
            p += bfu(v0.x & 0xffff) * yr[0] + bfu(v0.x >> 16) * yr[1]
               + bfu(v0.y & 0xffff) * yr[2] + bfu(v0.y >> 16) * yr[3]
               + bfu(v0.z & 0xffff) * yr[4] + bfu(v0.z >> 16) * yr[5]
               + bfu(v0.w & 0xffff) * yr[6] + bfu(v0.w >> 16) * yr[7];
            p += bfu(v1.x & 0xffff) * yr[8]  + bfu(v1.x >> 16) * yr[9]
               + bfu(v1.y & 0xffff) * yr[10] + bfu(v1.y >> 16) * yr[11]
               + bfu(v1.z & 0xffff) * yr[12] + bfu(v1.z >> 16) * yr[13]
               + bfu(v1.w & 0xffff) * yr[14] + bfu(v1.w >> 16) * yr[15];
        }
#pragma unroll
        for (int off = 32; off > 0; off >>= 1)
            p += __shfl_xor(p, off, 64);
        if (lane == 0) {
            float z = p + ld1(bo, n, ISF);
            u[n] = y0[n] + fmaxf(z, 0.f);     // reuse u as y1
        }
    }
    __syncthreads();
    ls = 0.f; ls2 = 0.f;
#pragma unroll
    for (int j = 0; j < 2; j++) {
        int c = t + 512 * j; float v = u[c]; ls += v; ls2 += v * v;
    }
    red[t] = ls; __syncthreads();
    for (int s2 = 256; s2 > 0; s2 >>= 1) { if (t < s2) red[t] += red[t + s2]; __syncthreads(); }
    mu = red[0] / DVX; __syncthreads();
    red[t] = ls2; __syncthreads();
    for (int s2 = 256; s2 > 0; s2 >>= 1) { if (t < s2) red[t] += red[t + s2]; __syncthreads(); }
    var = red[0] / DVX - mu * mu;
    r = rsqrtf(var + EPSF);
#pragma unroll
    for (int j = 0; j < 2; j++) {
        int c = t + 512 * j;
        float v = (u[c] - mu) * r * ld1(g1, c, ISF) + ld1(be1, c, ISF);
        if (ISF) ((float*)out)[(size_t)bq * DVX + c] = v;
        else     ((u16*)out)[(size_t)bq * DVX + c] = f2b(v);
    }
}

__global__ __launch_bounds__(512) void epi_kernel(
        const int* __restrict__ flag,
        const float* __restrict__ Oat, const void* __restrict__ S,
        const void* __restrict__ Wo, const void* __restrict__ bo,
        const void* __restrict__ g0, const void* __restrict__ be0,
        const void* __restrict__ g1, const void* __restrict__ be1,
        void* __restrict__ out) {
    __shared__ float u[DVX];
    __shared__ float y0[DVX];
    __shared__ float red[512];
    if (*flag) epi_body<true>(u, y0, red, Oat, S, Wo, bo, g0, be0, g1, be1, out);
    else       epi_body<false>(u, y0, red, Oat, S, Wo, bo, g0, be0, g1, be1, out);
}

extern "C" void kernel_launch(void* const* d_in, const int* in_sizes, int n_in,
                              void* d_out, int out_size, void* d_ws, size_t ws_size,
                              hipStream_t stream) {
    (void)in_sizes; (void)n_in; (void)out_size;
    const void* X    = d_in[0];
    const int* pad   = (const int*)d_in[1];
    const void* S    = d_in[2];
    const void* Wq   = d_in[3];
    const void* bq   = d_in[4];
    const void* Wk   = d_in[5];
    const void* bk   = d_in[6];
    const void* Wv   = d_in[7];
    const void* bv   = d_in[8];
    const void* Wo   = d_in[9];
    const void* bo   = d_in[10];
    const void* g0   = d_in[11];
    const void* be0  = d_in[12];
    const void* g1   = d_in[13];
    const void* be1  = d_in[14];

    char* ws = (char*)d_ws;
    int*   flag = (int*)ws;                                // 256 B reserved
    float* Qp  = (float*)(ws + 256);                       // 128 KiB
    float* Oat = (float*)(ws + 256 + 131072);              // 1 MiB
    u16*   Kp  = (u16*)(ws + 256 + 131072 + 1048576);      // 32 MiB
    u16*   Vp  = Kp + (size_t)BX * LX * DVX;               // 32 MiB
    u16*   Xb  = Vp + (size_t)BX * LX * DVX;               // 128 MiB (bf16 X)
    u16*   Wkb = Xb + (size_t)BX * LX * DIMX;              // 8 MiB
    u16*   Wvb = Wkb + (size_t)DVX * DIMX;                 // 8 MiB

    size_t need = 256 + 131072 + 1048576
                + 2 * (size_t)BX * LX * DVX * 2
                + (size_t)BX * LX * DIMX * 2
                + 2 * (size_t)DVX * DIMX * 2;              // ~209 MiB

    // One-time: allow 128 KiB dynamic LDS for kv_gemm3 (fallback if refused)
    static int attr_ok = -1;
    if (attr_ok < 0) {
        hipError_t e = hipFuncSetAttribute(
            reinterpret_cast<const void*>(kv_gemm3),
            hipFuncAttributeMaxDynamicSharedMemorySize, 131072);
        attr_ok = (e == hipSuccess) ? 1 : 0;
    }

    detect_kernel<<<1, 256, 0, stream>>>((const u16*)X, flag);
    qp_kernel<<<8192, 256, 0, stream>>>(flag, S, Wq, bq, Qp);

    if (ws_size >= need) {
        cvt_kernel<<<2048, 256, 0, stream>>>(flag, (const float*)X, Xb,
                                             BX * LX * DIMX / 8);
        cvt_kernel<<<512, 256, 0, stream>>>(flag, (const float*)Wk, Wkb,
                                            DVX * DIMX / 8);
        cvt_kernel<<<512, 256, 0, stream>>>(flag, (const float*)Wv, Wvb,
                                            DVX * DIMX / 8);
        if (attr_ok == 1) {
            kv_gemm3<<<512, 512, 131072, stream>>>(flag, X, Xb, Wk, bk, Wv, bv,
                                                   Wkb, Wvb, Kp, Vp);
        } else {
            kv_gemm2<<<2048, 256, 0, stream>>>(flag, X, Xb, Wk, bk, Wv, bv,
                                               Wkb, Wvb, Kp, Vp);
        }
    } else {
        kv_gemm<<<2048, 256, 0, stream>>>(flag, X, Wk, bk, Wv, bv, Kp, Vp);
    }

    attn_kernel<<<BX * HX * (NSX / QG), 256, 0, stream>>>(Qp, Kp, Vp, pad, Oat);
    epi_kernel<<<BX * NSX, 512, 0, stream>>>(flag, Oat, S, Wo, bo, g0, be0, g1, be1, (void*)d_out);
}

// Round 4
// 887.091 us; speedup vs baseline: 1.3502x; 1.2621x over previous
//
#include <hip/hip_runtime.h>

#define DIMX 4096
#define DVX  1024
#define HX   16
#define DHX  64
#define NSX  32
#define BX   8
#define LX   2048
#define EPSF 1e-5f

typedef unsigned short u16;
typedef unsigned int   u32;

using bf16x8 = __attribute__((ext_vector_type(8))) __bf16;
using f32x4  = __attribute__((ext_vector_type(4))) float;

__device__ __forceinline__ float bfu(u16 u) {
    union { u32 i; float f; } c; c.i = ((u32)u) << 16; return c.f;
}
__device__ __forceinline__ u16 f2b(float f) {
    union { float f; u32 u; } c; c.f = f;
    u32 u = c.u;
    u32 r = (u + 0x7fffu + ((u >> 16) & 1u)) >> 16;
    return (u16)r;
}

// async global->LDS DMA, 16B per lane; LDS dest = wave-uniform base + lane*16
__device__ __forceinline__ void async16(const u16* g, u16* l) {
    __builtin_amdgcn_global_load_lds(
        (const __attribute__((address_space(1))) void*)g,
        (__attribute__((address_space(3))) void*)l, 16, 0, 0);
}

// load 8 logical elements (idx multiple of 8, 16B-aligned base) as fp32
template<bool ISF>
__device__ __forceinline__ void ld8(const void* base, size_t idx, float o[8]) {
    if (ISF) {
        const float* f = (const float*)base + idx;
        float4 a = *(const float4*)f, b = *(const float4*)(f + 4);
        o[0]=a.x; o[1]=a.y; o[2]=a.z; o[3]=a.w;
        o[4]=b.x; o[5]=b.y; o[6]=b.z; o[7]=b.w;
    } else {
        const u16* h = (const u16*)base + idx;
        uint4 v = *(const uint4*)h;
        o[0]=bfu(v.x & 0xffff); o[1]=bfu(v.x >> 16);
        o[2]=bfu(v.y & 0xffff); o[3]=bfu(v.y >> 16);
        o[4]=bfu(v.z & 0xffff); o[5]=bfu(v.z >> 16);
        o[6]=bfu(v.w & 0xffff); o[7]=bfu(v.w >> 16);
    }
}
__device__ __forceinline__ float ld1(const void* base, size_t idx, bool isf) {
    return isf ? ((const float*)base)[idx] : bfu(((const u16*)base)[idx]);
}

// ---------------- K0: dtype detector -------------------------------------
__global__ __launch_bounds__(256) void detect_kernel(const u16* __restrict__ X,
                                                     int* __restrict__ flag) {
    __shared__ int cnt;
    if (threadIdx.x == 0) cnt = 0;
    __syncthreads();
    int local = 0;
    for (int i = threadIdx.x; i < 8192; i += 256) {
        u32 e = ((u32)X[i] >> 7) & 0xffu;
        if (e >= 200u) local++;
    }
    atomicAdd(&cnt, local);
    __syncthreads();
    if (threadIdx.x == 0) *flag = (cnt > 32) ? 1 : 0;
}

// ---------------- K0b: fp32 -> bf16 bulk converter -------------------------
__global__ __launch_bounds__(256) void cvt_kernel(const int* __restrict__ flag,
                                                  const float* __restrict__ src,
                                                  u16* __restrict__ dst, int ngrp) {
    if (*flag == 0) return;
    int stride = gridDim.x * 256;
    for (int i = blockIdx.x * 256 + threadIdx.x; i < ngrp; i += stride) {
        const float4* f = (const float4*)(src + (size_t)i * 8);
        float4 a = f[0], b = f[1];
        uint4 r;
        r.x = (u32)f2b(a.x) | ((u32)f2b(a.y) << 16);
        r.y = (u32)f2b(a.z) | ((u32)f2b(a.w) << 16);
        r.z = (u32)f2b(b.x) | ((u32)f2b(b.y) << 16);
        r.w = (u32)f2b(b.z) | ((u32)f2b(b.w) << 16);
        *(uint4*)(dst + (size_t)i * 8) = r;
    }
}

// ---------------- K1: Qp = S @ Wq^T + bq  -- wave-per-output GEMV ----------
__global__ __launch_bounds__(256) void qp_kernel(
        const int* __restrict__ flag, const void* __restrict__ S,
        const void* __restrict__ Wq, const void* __restrict__ bq,
        float* __restrict__ Qp) {
    int wid = blockIdx.x * 4 + (threadIdx.x >> 6);   // 0..32767
    int lane = threadIdx.x & 63;
    int q = wid >> 10, n = wid & 1023;
    bool isf = (*flag != 0);
    float p = 0.f;
    if (isf) {
        const float* srow = (const float*)S + (size_t)q * DVX + lane * 16;
        const float* wrow = (const float*)Wq + (size_t)n * DVX + lane * 16;
#pragma unroll
        for (int e = 0; e < 16; e += 4) {
            float4 a = *(const float4*)(srow + e);
            float4 b = *(const float4*)(wrow + e);
            p += a.x * b.x + a.y * b.y + a.z * b.z + a.w * b.w;
        }
    } else {
        const u16* srow = (const u16*)S + (size_t)q * DVX + lane * 16;
        const u16* wrow = (const u16*)Wq + (size_t)n * DVX + lane * 16;
#pragma unroll
        for (int c = 0; c < 2; c++) {
            uint4 a = *(const uint4*)(srow + c * 8);
            uint4 b = *(const uint4*)(wrow + c * 8);
            p += bfu(a.x & 0xffff) * bfu(b.x & 0xffff) + bfu(a.x >> 16) * bfu(b.x >> 16)
               + bfu(a.y & 0xffff) * bfu(b.y & 0xffff) + bfu(a.y >> 16) * bfu(b.y >> 16)
               + bfu(a.z & 0xffff) * bfu(b.z & 0xffff) + bfu(a.z >> 16) * bfu(b.z >> 16)
               + bfu(a.w & 0xffff) * bfu(b.w & 0xffff) + bfu(a.w >> 16) * bfu(b.w >> 16);
        }
    }
#pragma unroll
    for (int off = 32; off > 0; off >>= 1)
        p += __shfl_xor(p, off, 64);
    if (lane == 0) Qp[wid] = p + ld1(bq, n, isf);
}

// ---------------- K2a: 256x256 BK=64 phase-pipelined GEMM (T2+T3+T4+T5) ----
__global__ __launch_bounds__(512, 2) void kv_gemm3(
        const int* __restrict__ flag,
        const void* __restrict__ X,  const u16* __restrict__ Xb,
        const void* __restrict__ Wk, const void* __restrict__ bk,
        const void* __restrict__ Wv, const void* __restrict__ bv,
        const u16* __restrict__ Wkb, const u16* __restrict__ Wvb,
        u16* __restrict__ Kp, u16* __restrict__ Vp) {
    extern __shared__ __align__(16) u16 lds[];   // 65536 elems = 128 KiB
    const bool isf = (*flag != 0);
    const u16* Xs = isf ? Xb : (const u16*)X;

    const int t = threadIdx.x;
    const int lane = t & 63, w = t >> 6;
    const int wm = w >> 2, wn = w & 3;
    const int quad = lane >> 4, l16 = lane & 15;
    const int l8 = l16 & 7;

    const int bid = blockIdx.x;
    const int swz = (bid & 7) * 64 + (bid >> 3);
    const int mt = swz >> 3, nt = swz & 7;
    const int m0 = mt * 256, n0 = nt * 256;

    const u16* Wb16; const void* bias; int boff;
    if (n0 < DVX) { Wb16 = (isf ? Wkb : (const u16*)Wk) + (size_t)n0 * DIMX;
                    bias = bk; boff = n0; }
    else          { Wb16 = (isf ? Wvb : (const u16*)Wv) + (size_t)(n0 - DVX) * DIMX;
                    bias = bv; boff = n0 - DVX; }

    f32x4 acc[8][4];
#pragma unroll
    for (int i = 0; i < 8; i++)
#pragma unroll
        for (int j = 0; j < 4; j++) acc[i][j] = {0.f, 0.f, 0.f, 0.f};

    {
        u16* An = lds;
        u16* Bn = lds + 32768;
#pragma unroll
        for (int i = 0; i < 4; i++) {
            int gi = i * 512 + t;
            int r = gi >> 3;
            int g = (gi & 7) ^ (r & 7);
            async16(Xs + (size_t)(m0 + r) * DIMX + g * 8, An + gi * 8);
        }
#pragma unroll
        for (int i = 0; i < 4; i++) {
            int gi = i * 512 + t;
            int r = gi >> 3;
            int g = (gi & 7) ^ (r & 7);
            async16(Wb16 + (size_t)r * DIMX + g * 8, Bn + gi * 8);
        }
        asm volatile("s_waitcnt vmcnt(0)" ::: "memory");
        __builtin_amdgcn_s_barrier();
    }

    for (int kt = 0; kt < DIMX / 64; kt++) {
        u16* Ab = lds + (kt & 1) * 16384;
        u16* Bb = lds + 32768 + (kt & 1) * 16384;
        u16* An = lds + ((kt + 1) & 1) * 16384;
        u16* Bn = lds + 32768 + ((kt + 1) & 1) * 16384;
        const int k1 = (kt + 1) * 64;
        const bool st = (kt + 1) < (DIMX / 64);

        bf16x8 bfr[4][2];
#pragma unroll
        for (int ni = 0; ni < 4; ni++)
#pragma unroll
            for (int ks = 0; ks < 2; ks++) {
                int R = wn * 64 + ni * 16 + l16;
                int cc = ((ks * 4 + quad) ^ l8);
                bfr[ni][ks] = *(const bf16x8*)&Bb[R * 64 + cc * 8];
            }
        {
            bf16x8 a[2][2];
#pragma unroll
            for (int dm = 0; dm < 2; dm++)
#pragma unroll
                for (int ks = 0; ks < 2; ks++) {
                    int R = wm * 128 + dm * 16 + l16;
                    int cc = ((ks * 4 + quad) ^ l8);
                    a[dm][ks] = *(const bf16x8*)&Ab[R * 64 + cc * 8];
                }
            if (st) {
#pragma unroll
                for (int i = 0; i < 4; i++) {
                    int gi = i * 512 + t;
                    int r = gi >> 3;
                    int g = (gi & 7) ^ (r & 7);
                    async16(Xs + (size_t)(m0 + r) * DIMX + k1 + g * 8, An + gi * 8);
                }
#pragma unroll
                for (int i = 0; i < 4; i++) {
                    int gi = i * 512 + t;
                    int r = gi >> 3;
                    int g = (gi & 7) ^ (r & 7);
                    async16(Wb16 + (size_t)r * DIMX + k1 + g * 8, Bn + gi * 8);
                }
            }
            __builtin_amdgcn_s_setprio(1);
#pragma unroll
            for (int dm = 0; dm < 2; dm++)
#pragma unroll
                for (int ni = 0; ni < 4; ni++)
#pragma unroll
                    for (int ks = 0; ks < 2; ks++)
                        acc[dm][ni] = __builtin_amdgcn_mfma_f32_16x16x32_bf16(
                            a[dm][ks], bfr[ni][ks], acc[dm][ni], 0, 0, 0);
            __builtin_amdgcn_s_setprio(0);
        }
        __builtin_amdgcn_s_barrier();

#pragma unroll
        for (int p = 1; p < 4; p++) {
            bf16x8 a[2][2];
#pragma unroll
            for (int dm = 0; dm < 2; dm++)
#pragma unroll
                for (int ks = 0; ks < 2; ks++) {
                    int R = wm * 128 + (2 * p + dm) * 16 + l16;
                    int cc = ((ks * 4 + quad) ^ l8);
                    a[dm][ks] = *(const bf16x8*)&Ab[R * 64 + cc * 8];
                }
            __builtin_amdgcn_s_setprio(1);
#pragma unroll
            for (int dm = 0; dm < 2; dm++)
#pragma unroll
                for (int ni = 0; ni < 4; ni++)
#pragma unroll
                    for (int ks = 0; ks < 2; ks++)
                        acc[2 * p + dm][ni] = __builtin_amdgcn_mfma_f32_16x16x32_bf16(
                            a[dm][ks], bfr[ni][ks], acc[2 * p + dm][ni], 0, 0, 0);
            __builtin_amdgcn_s_setprio(0);
            if (p < 3) __builtin_amdgcn_s_barrier();
        }

        __builtin_amdgcn_sched_barrier(0);
        asm volatile("s_waitcnt vmcnt(0)" ::: "memory");
        __builtin_amdgcn_s_barrier();
        __builtin_amdgcn_sched_barrier(0);
    }

    float bb[4];
#pragma unroll
    for (int ni = 0; ni < 4; ni++)
        bb[ni] = ld1(bias, (size_t)(boff + wn * 64 + ni * 16 + l16), isf);
#pragma unroll
    for (int mi = 0; mi < 8; mi++) {
#pragma unroll
        for (int ni = 0; ni < 4; ni++) {
            int colL = wn * 64 + ni * 16 + l16;
            int col = n0 + colL;
            u16* dst; int dcol;
            if (col < DVX) { dst = Kp; dcol = col; }
            else           { dst = Vp; dcol = col - DVX; }
#pragma unroll
            for (int r = 0; r < 4; r++) {
                int row = m0 + wm * 128 + mi * 16 + quad * 4 + r;
                dst[(size_t)row * DVX + dcol] = f2b(acc[mi][ni][r] + bb[ni]);
            }
        }
    }
}

// ---------------- K2b: 128x128 m97-structure GEMM (fallback fast path) -----
#define TM 128
#define TN 128
#define BKK 32
#define LDT 32

__device__ __forceinline__ uint4 pack8(float o[8]) {
    uint4 r;
    r.x = (u32)f2b(o[0]) | ((u32)f2b(o[1]) << 16);
    r.y = (u32)f2b(o[2]) | ((u32)f2b(o[3]) << 16);
    r.z = (u32)f2b(o[4]) | ((u32)f2b(o[5]) << 16);
    r.w = (u32)f2b(o[6]) | ((u32)f2b(o[7]) << 16);
    return r;
}

__global__ __launch_bounds__(256) void kv_gemm2(
        const int* __restrict__ flag,
        const void* __restrict__ X,  const u16* __restrict__ Xb,
        const void* __restrict__ Wk, const void* __restrict__ bk,
        const void* __restrict__ Wv, const void* __restrict__ bv,
        const u16* __restrict__ Wkb, const u16* __restrict__ Wvb,
        u16* __restrict__ Kp, u16* __restrict__ Vp) {
    __shared__ u16 As[TM * LDT];
    __shared__ u16 Bs[TN * LDT];
    const bool isf = (*flag != 0);
    const u16* Xs = isf ? Xb : (const u16*)X;

    const int t = threadIdx.x;
    const int lane = t & 63, w = t >> 6;
    const int wm = w >> 1, wn = w & 1;
    const int quad = lane >> 4, l16 = lane & 15;
    const int bl = blockIdx.x;
    const int xcd = bl & 7, bq = bl >> 3;
    const int m0 = (xcd + 8 * (bq >> 4)) * TM;
    const int n0 = (bq & 15) * TN;
    const u16* Wb16; const void* bias; int boff;
    if (n0 < DVX) { Wb16 = (isf ? Wkb : (const u16*)Wk) + (size_t)n0 * DIMX;
                    bias = bk; boff = n0; }
    else          { Wb16 = (isf ? Wvb : (const u16*)Wv) + (size_t)(n0 - DVX) * DIMX;
                    bias = bv; boff = n0 - DVX; }

    f32x4 acc[4][4];
#pragma unroll
    for (int i = 0; i < 4; i++)
#pragma unroll
        for (int j = 0; j < 4; j++) acc[i][j] = {0.f, 0.f, 0.f, 0.f};

    const int srow = lane >> 2;
    const int gcol = ((lane & 3) ^ ((lane >> 3) & 3)) * 8;
    const int ph = (l16 >> 1) & 3;

    for (int k0 = 0; k0 < DIMX; k0 += BKK) {
        __syncthreads();
#pragma unroll
        for (int c = 0; c < 2; c++) {
            int rr = w * 32 + c * 16;
            async16(Xs + (size_t)(m0 + rr + srow) * DIMX + k0 + gcol,
                    As + rr * LDT);
            async16(Wb16 + (size_t)(rr + srow) * DIMX + k0 + gcol,
                    Bs + rr * LDT);
        }
        __syncthreads();
        bf16x8 af[4], bfr[4];
#pragma unroll
        for (int mi = 0; mi < 4; mi++) {
            int ar = wm * 64 + mi * 16 + l16;
            af[mi] = *(const bf16x8*)&As[ar * LDT + (quad ^ ph) * 8];
        }
#pragma unroll
        for (int ni = 0; ni < 4; ni++) {
            int br = wn * 64 + ni * 16 + l16;
            bfr[ni] = *(const bf16x8*)&Bs[br * LDT + (quad ^ ph) * 8];
        }
#pragma unroll
        for (int mi = 0; mi < 4; mi++)
#pragma unroll
            for (int ni = 0; ni < 4; ni++)
                acc[mi][ni] = __builtin_amdgcn_mfma_f32_16x16x32_bf16(
                    af[mi], bfr[ni], acc[mi][ni], 0, 0, 0);
    }

#pragma unroll
    for (int mi = 0; mi < 4; mi++) {
#pragma unroll
        for (int ni = 0; ni < 4; ni++) {
            int colL = wn * 64 + ni * 16 + l16;
            int col = n0 + colL;
            float bb = ld1(bias, (size_t)(boff + colL), isf);
            u16* dst; int dcol;
            if (col < DVX) { dst = Kp; dcol = col; }
            else           { dst = Vp; dcol = col - DVX; }
#pragma unroll
            for (int r = 0; r < 4; r++) {
                int row = m0 + wm * 64 + mi * 16 + quad * 4 + r;
                dst[(size_t)row * DVX + dcol] = f2b(acc[mi][ni][r] + bb);
            }
        }
    }
}

// -------- fallback path (small workspace): original dual-dtype body --------
template<bool ISF>
__device__ void kv_body(const void* __restrict__ X,
                        const void* __restrict__ Wk, const void* __restrict__ bk,
                        const void* __restrict__ Wv, const void* __restrict__ bv,
                        u16* __restrict__ Kp, u16* __restrict__ Vp,
                        u16* As, u16* Bs) {
    const int t = threadIdx.x;
    const int lane = t & 63, w = t >> 6;
    const int wm = w >> 1, wn = w & 1;
    const int quad = lane >> 4, l16 = lane & 15;
    const int bl = blockIdx.x;
    const int xcd = bl & 7, bq = bl >> 3;
    const int m0 = (xcd + 8 * (bq >> 4)) * TM;
    const int n0 = (bq & 15) * TN;
    const void* Wbase; const void* bias; int boff;
    size_t woff;
    if (n0 < DVX) { Wbase = Wk; bias = bk; woff = (size_t)n0 * DIMX; boff = n0; }
    else          { Wbase = Wv; bias = bv; woff = (size_t)(n0 - DVX) * DIMX; boff = n0 - DVX; }
    const u16* Wb16 = (const u16*)Wbase + woff;
    const float* Wbf = (const float*)Wbase + woff;

    f32x4 acc[4][4];
#pragma unroll
    for (int i = 0; i < 4; i++)
#pragma unroll
        for (int j = 0; j < 4; j++) acc[i][j] = {0.f, 0.f, 0.f, 0.f};

    const int srow = lane >> 2;
    const int gcol = ((lane & 3) ^ ((lane >> 3) & 3)) * 8;
    const int ph = (l16 >> 1) & 3;
    const int r0 = t >> 2, c0 = (t & 3) * 8;
    const int r1 = r0 + 64;
    const int swc = (((t & 3) ^ ((r0 >> 1) & 3))) * 8;

    for (int k0 = 0; k0 < DIMX; k0 += BKK) {
        if constexpr (ISF) {
            float oa0[8], oa1[8], ob0[8], ob1[8];
            ld8<true>(X,   (size_t)(m0 + r0) * DIMX + k0 + c0, oa0);
            ld8<true>(X,   (size_t)(m0 + r1) * DIMX + k0 + c0, oa1);
            ld8<true>(Wbf, (size_t)r0 * DIMX + k0 + c0, ob0);
            ld8<true>(Wbf, (size_t)r1 * DIMX + k0 + c0, ob1);
            __syncthreads();
            *(uint4*)&As[r0 * LDT + swc] = pack8(oa0);
            *(uint4*)&As[r1 * LDT + swc] = pack8(oa1);
            *(uint4*)&Bs[r0 * LDT + swc] = pack8(ob0);
            *(uint4*)&Bs[r1 * LDT + swc] = pack8(ob1);
        } else {
            __syncthreads();
#pragma unroll
            for (int c = 0; c < 2; c++) {
                int rr = w * 32 + c * 16;
                async16((const u16*)X + (size_t)(m0 + rr + srow) * DIMX + k0 + gcol,
                        As + rr * LDT);
                async16(Wb16 + (size_t)(rr + srow) * DIMX + k0 + gcol,
                        Bs + rr * LDT);
            }
        }
        __syncthreads();
        bf16x8 af[4], bfr[4];
#pragma unroll
        for (int mi = 0; mi < 4; mi++) {
            int ar = wm * 64 + mi * 16 + l16;
            af[mi] = *(const bf16x8*)&As[ar * LDT + (quad ^ ph) * 8];
        }
#pragma unroll
        for (int ni = 0; ni < 4; ni++) {
            int br = wn * 64 + ni * 16 + l16;
            bfr[ni] = *(const bf16x8*)&Bs[br * LDT + (quad ^ ph) * 8];
        }
#pragma unroll
        for (int mi = 0; mi < 4; mi++)
#pragma unroll
            for (int ni = 0; ni < 4; ni++)
                acc[mi][ni] = __builtin_amdgcn_mfma_f32_16x16x32_bf16(
                    af[mi], bfr[ni], acc[mi][ni], 0, 0, 0);
    }

#pragma unroll
    for (int mi = 0; mi < 4; mi++) {
#pragma unroll
        for (int ni = 0; ni < 4; ni++) {
            int colL = wn * 64 + ni * 16 + l16;
            int col = n0 + colL;
            float bb = ld1(bias, (size_t)(boff + colL), ISF);
            u16* dst; int dcol;
            if (col < DVX) { dst = Kp; dcol = col; }
            else           { dst = Vp; dcol = col - DVX; }
#pragma unroll
            for (int r = 0; r < 4; r++) {
                int row = m0 + wm * 64 + mi * 16 + quad * 4 + r;
                dst[(size_t)row * DVX + dcol] = f2b(acc[mi][ni][r] + bb);
            }
        }
    }
}

__global__ __launch_bounds__(256) void kv_gemm(
        const int* __restrict__ flag, const void* __restrict__ X,
        const void* __restrict__ Wk, const void* __restrict__ bk,
        const void* __restrict__ Wv, const void* __restrict__ bv,
        u16* __restrict__ Kp, u16* __restrict__ Vp) {
    __shared__ u16 As[TM * LDT];
    __shared__ u16 Bs[TN * LDT];
    if (*flag) kv_body<true>(X, Wk, bk, Wv, bv, Kp, Vp, As, Bs);
    else       kv_body<false>(X, Wk, bk, Wv, bv, Kp, Vp, As, Bs);
}

// ---------------- K3a: split-K attention chunk kernel ----------------------
// One block per (b, h, chunk of 256 keys); all 32 seeds per block.
// Unique K/V reads (64 MB total fetch vs 262 MB for the old per-qgroup
// layout). Zero barriers: each wave owns 8 queries end-to-end; V rows are
// read once per block (4x intra-block via L1). Partials (O_c, m_c, l_c)
// combined exactly by attn_combine (split-softmax identity).
#define CHK 256
#define NCH (LX / CHK)                      // 8
__global__ __launch_bounds__(256) void attn2_kernel(
        const float* __restrict__ Qp, const u16* __restrict__ Kp,
        const u16* __restrict__ Vp, const int* __restrict__ pad,
        float* __restrict__ Opart, float* __restrict__ Ml) {
    __shared__ float sc[NSX * CHK];         // 32 KB
    const int blk = blockIdx.x;             // b*HX*NCH + h*NCH + c0
    const int b  = blk / (HX * NCH);
    const int h  = (blk / NCH) % HX;
    const int c0 = blk % NCH;
    const int t = threadIdx.x;
    const int w = t >> 6, lane = t & 63;
    const int rsub = lane >> 3;             // key row within octet (0..7)
    const int dsub = lane & 7;              // d-chunk (0..7)
    const int q0w = w * 8;                  // this wave's 8 queries

    // Q fragments: qc[qq][e] = Qp[q0w+qq][h*64 + dsub*8 + e]
    float qc[8][8];
#pragma unroll
    for (int qq = 0; qq < 8; qq++) {
        const float* qp = Qp + (size_t)(q0w + qq) * DVX + h * DHX + dsub * 8;
        float4 a = *(const float4*)qp, bq4 = *(const float4*)(qp + 4);
        qc[qq][0]=a.x; qc[qq][1]=a.y; qc[qq][2]=a.z; qc[qq][3]=a.w;
        qc[qq][4]=bq4.x; qc[qq][5]=bq4.y; qc[qq][6]=bq4.z; qc[qq][7]=bq4.w;
    }

    const u16* kb = Kp + ((size_t)b * LX + c0 * CHK) * DVX + h * DHX;
    const int* pb = pad + b * LX + c0 * CHK;

    // ---- phase 1: scores for 8 q x 256 k -> sc, track per-q max ----
    float lmax[8];
#pragma unroll
    for (int qq = 0; qq < 8; qq++) lmax[qq] = -3e38f;
    for (int i = 0; i < CHK / 8; i++) {
        int k = i * 8 + rsub;
        uint4 v = *(const uint4*)(kb + (size_t)k * DVX + dsub * 8);
        float kf[8];
        kf[0]=bfu(v.x & 0xffff); kf[1]=bfu(v.x >> 16);
        kf[2]=bfu(v.y & 0xffff); kf[3]=bfu(v.y >> 16);
        kf[4]=bfu(v.z & 0xffff); kf[5]=bfu(v.z >> 16);
        kf[6]=bfu(v.w & 0xffff); kf[7]=bfu(v.w >> 16);
        int pm = pb[k];
#pragma unroll
        for (int qq = 0; qq < 8; qq++) {
            float s = kf[0]*qc[qq][0] + kf[1]*qc[qq][1]
                    + kf[2]*qc[qq][2] + kf[3]*qc[qq][3]
                    + kf[4]*qc[qq][4] + kf[5]*qc[qq][5]
                    + kf[6]*qc[qq][6] + kf[7]*qc[qq][7];
            s += __shfl_xor(s, 1, 64);
            s += __shfl_xor(s, 2, 64);
            s += __shfl_xor(s, 4, 64);
            s *= 0.03125f;
            s = pm ? s : -1e30f;
            if (dsub == 0) sc[(q0w + qq) * CHK + k] = s;
            lmax[qq] = fmaxf(lmax[qq], s);
        }
    }
    // reduce max over the 8 key-octet groups (lane bits 3..5)
#pragma unroll
    for (int qq = 0; qq < 8; qq++) {
        lmax[qq] = fmaxf(lmax[qq], __shfl_xor(lmax[qq], 8, 64));
        lmax[qq] = fmaxf(lmax[qq], __shfl_xor(lmax[qq], 16, 64));
        lmax[qq] = fmaxf(lmax[qq], __shfl_xor(lmax[qq], 32, 64));
    }

    // ---- phase 2: exp + per-q sum (wave-local rows only, no barrier) ----
#pragma unroll
    for (int qq = 0; qq < 8; qq++) {
        float m = lmax[qq];
        float lsum = 0.f;
#pragma unroll
        for (int it = 0; it < CHK / 64; it++) {
            int idx = (q0w + qq) * CHK + it * 64 + lane;
            float sv = sc[idx];
            float e = (sv > -1e29f) ? __expf(sv - m) : 0.f;
            sc[idx] = e;
            lsum += e;
        }
#pragma unroll
        for (int off = 32; off > 0; off >>= 1)
            lsum += __shfl_xor(lsum, off, 64);
        if (lane == 0) {
            Ml[(size_t)blk * 64 + (q0w + qq) * 2 + 0] = m;
            Ml[(size_t)blk * 64 + (q0w + qq) * 2 + 1] = lsum;
        }
    }

    // ---- phase 3: PV, single pass over V rows; acc per (q, d-chunk) ----
    float acc[8][8];
#pragma unroll
    for (int qq = 0; qq < 8; qq++)
#pragma unroll
        for (int e = 0; e < 8; e++) acc[qq][e] = 0.f;
    const u16* vb = Vp + ((size_t)b * LX + c0 * CHK) * DVX + h * DHX + dsub * 8;
    for (int i = 0; i < CHK / 8; i++) {
        int k = i * 8 + rsub;
        uint4 v = *(const uint4*)(vb + (size_t)k * DVX);
        float vf[8];
        vf[0]=bfu(v.x & 0xffff); vf[1]=bfu(v.x >> 16);
        vf[2]=bfu(v.y & 0xffff); vf[3]=bfu(v.y >> 16);
        vf[4]=bfu(v.z & 0xffff); vf[5]=bfu(v.z >> 16);
        vf[6]=bfu(v.w & 0xffff); vf[7]=bfu(v.w >> 16);
#pragma unroll
        for (int qq = 0; qq < 8; qq++) {
            float p = sc[(q0w + qq) * CHK + k];
#pragma unroll
            for (int e = 0; e < 8; e++) acc[qq][e] += p * vf[e];
        }
    }
    // reduce over key-octet groups (lane bits 3..5), then lane rsub==qq writes
#pragma unroll
    for (int qq = 0; qq < 8; qq++) {
#pragma unroll
        for (int e = 0; e < 8; e++) {
            acc[qq][e] += __shfl_xor(acc[qq][e], 8, 64);
            acc[qq][e] += __shfl_xor(acc[qq][e], 16, 64);
            acc[qq][e] += __shfl_xor(acc[qq][e], 32, 64);
        }
        if (rsub == qq) {
            float* op = Opart + ((size_t)blk * NSX + q0w + qq) * DHX + dsub * 8;
            float4 r0 = {acc[qq][0], acc[qq][1], acc[qq][2], acc[qq][3]};
            float4 r1 = {acc[qq][4], acc[qq][5], acc[qq][6], acc[qq][7]};
            *(float4*)op = r0;
            *(float4*)(op + 4) = r1;
        }
    }
}

// ---------------- K3b: combine split-K partials ----------------------------
__global__ __launch_bounds__(256) void attn_combine(
        const float* __restrict__ Opart, const float* __restrict__ Ml,
        float* __restrict__ Oat) {
    const int bh = blockIdx.x;              // 0..127
    const int b = bh / HX, h = bh % HX;
    const int t = threadIdx.x;
    const int q = t >> 3, d0 = (t & 7) * 8;
    const size_t cbase = (size_t)bh * NCH;
    float m = -3e38f;
#pragma unroll
    for (int c = 0; c < NCH; c++)
        m = fmaxf(m, Ml[(cbase + c) * 64 + q * 2]);
    float l = 0.f, o[8];
#pragma unroll
    for (int e = 0; e < 8; e++) o[e] = 0.f;
#pragma unroll
    for (int c = 0; c < NCH; c++) {
        float mc = Ml[(cbase + c) * 64 + q * 2 + 0];
        float lc = Ml[(cbase + c) * 64 + q * 2 + 1];
        float wgt = (mc > -1e29f) ? __expf(mc - m) : 0.f;
        l += wgt * lc;
        const float* op = Opart + ((cbase + c) * NSX + q) * DHX + d0;
        float4 x = *(const float4*)op, y = *(const float4*)(op + 4);
        o[0] += wgt * x.x; o[1] += wgt * x.y; o[2] += wgt * x.z; o[3] += wgt * x.w;
        o[4] += wgt * y.x; o[5] += wgt * y.y; o[6] += wgt * y.z; o[7] += wgt * y.w;
    }
    float inv = (l > 0.f) ? 1.f / l : 0.f;
    float* dst = Oat + ((size_t)(b * NSX) + q) * DVX + h * DHX + d0;
    float4 r0 = {o[0]*inv, o[1]*inv, o[2]*inv, o[3]*inv};
    float4 r1 = {o[4]*inv, o[5]*inv, o[6]*inv, o[7]*inv};
    *(float4*)dst = r0;
    *(float4*)(dst + 4) = r1;
}

// ---------------- K3-legacy: old attention (workspace fallback) ------------
#define QG 4
__global__ __launch_bounds__(256) void attn_kernel(
        const float* __restrict__ Qp, const u16* __restrict__ Kp,
        const u16* __restrict__ Vp, const int* __restrict__ pad,
        float* __restrict__ Oat) {
    __shared__ float qv[QG * DHX];
    __shared__ float sc[QG * LX];
    __shared__ float rpart[256 * 8];
    __shared__ float invs[QG];
    const int blk = blockIdx.x;
    const int nqg = NSX / QG;
    const int b  = blk / (HX * nqg);
    const int h  = (blk / nqg) % HX;
    const int q0 = (blk % nqg) * QG;
    const int t = threadIdx.x;
    const int w = t >> 6, lane = t & 63;

    qv[t] = Qp[(size_t)(q0 + (t >> 6)) * DVX + h * DHX + (t & 63)];
    __syncthreads();

    const u16* Kb = Kp + (size_t)b * LX * DVX + h * DHX;
    const int rsub = lane >> 3;
    const int dsub = lane & 7;
    float qc[8];
#pragma unroll
    for (int e = 0; e < 8; e++) qc[e] = qv[w * DHX + dsub * 8 + e];

    float lmax = -3e38f;
    for (int i = 0; i < LX / 8; i++) {
        int k = i * 8 + rsub;
        uint4 v = *(const uint4*)(Kb + (size_t)k * DVX + dsub * 8);
        float s = bfu(v.x & 0xffff) * qc[0] + bfu(v.x >> 16) * qc[1]
                + bfu(v.y & 0xffff) * qc[2] + bfu(v.y >> 16) * qc[3]
                + bfu(v.z & 0xffff) * qc[4] + bfu(v.z >> 16) * qc[5]
                + bfu(v.w & 0xffff) * qc[6] + bfu(v.w >> 16) * qc[7];
        s += __shfl_xor(s, 1, 64);
        s += __shfl_xor(s, 2, 64);
        s += __shfl_xor(s, 4, 64);
        s *= 0.03125f;
        s = (pad[b * LX + k] != 0) ? s : -1e30f;
        if (dsub == 0) sc[w * LX + k] = s;
        lmax = fmaxf(lmax, s);
    }
#pragma unroll
    for (int off = 32; off > 0; off >>= 1)
        lmax = fmaxf(lmax, __shfl_xor(lmax, off, 64));
    float lsum = 0.f;
    for (int i = 0; i < LX / 64; i++) {
        int k = i * 64 + lane;
        float sv = sc[w * LX + k];
        float e = (sv > -1e29f) ? __expf(sv - lmax) : 0.f;
        sc[w * LX + k] = e;
        lsum += e;
    }
#pragma unroll
    for (int off = 32; off > 0; off >>= 1)
        lsum += __shfl_xor(lsum, off, 64);
    if (lane == 0) invs[w] = (lsum > 0.f) ? 1.f / lsum : 0.f;

    const int kg = (t >> 3) & 7, dg = t & 7;
    const u16* Vb = Vp + (size_t)b * LX * DVX + h * DHX + dg * 8;
    float a8[8];
#pragma unroll
    for (int e = 0; e < 8; e++) a8[e] = 0.f;
    for (int i = 0; i < LX / 8; i++) {
        int k = i * 8 + kg;
        float p = sc[w * LX + k];
        uint4 v = *(const uint4*)(Vb + (size_t)k * DVX);
        a8[0] += p * bfu(v.x & 0xffff); a8[1] += p * bfu(v.x >> 16);
        a8[2] += p * bfu(v.y & 0xffff); a8[3] += p * bfu(v.y >> 16);
        a8[4] += p * bfu(v.z & 0xffff); a8[5] += p * bfu(v.z >> 16);
        a8[6] += p * bfu(v.w & 0xffff); a8[7] += p * bfu(v.w >> 16);
    }
#pragma unroll
    for (int e = 0; e < 8; e++) rpart[t * 8 + e] = a8[e];
    __syncthreads();

    {
        int q = t >> 6, d = t & 63;
        float o = 0.f;
#pragma unroll
        for (int g = 0; g < 8; g++)
            o += rpart[(q * 64 + g * 8 + (d >> 3)) * 8 + (d & 7)];
        o *= invs[q];
        Oat[((size_t)(b * NSX + q0 + q)) * DVX + h * DHX + d] = o;
    }
}

// ---------------- K4: residual + LN0 + MLP(relu) residual + LN1 ------------
template<bool ISF>
__device__ void epi_body(float* u, float* y0, float* red,
                         const float* __restrict__ Oat, const void* __restrict__ S,
                         const void* __restrict__ Wo, const void* __restrict__ bo,
                         const void* __restrict__ g0, const void* __restrict__ be0,
                         const void* __restrict__ g1, const void* __restrict__ be1,
                         void* __restrict__ out) {
    const int bq = blockIdx.x;            // (b*32+q)
    const int q = bq & 31;
    const int t = threadIdx.x;
    const int w = t >> 6, lane = t & 63;

    float ls = 0.f, ls2 = 0.f;
#pragma unroll
    for (int j = 0; j < 2; j++) {
        int c = t + 512 * j;
        float v = ld1(S, (size_t)q * DVX + c, ISF) + Oat[(size_t)bq * DVX + c];
        u[c] = v; ls += v; ls2 += v * v;
    }
    red[t] = ls; __syncthreads();
    for (int s2 = 256; s2 > 0; s2 >>= 1) { if (t < s2) red[t] += red[t + s2]; __syncthreads(); }
    float mu = red[0] / DVX; __syncthreads();
    red[t] = ls2; __syncthreads();
    for (int s2 = 256; s2 > 0; s2 >>= 1) { if (t < s2) red[t] += red[t + s2]; __syncthreads(); }
    float var = red[0] / DVX - mu * mu;
    float r = rsqrtf(var + EPSF);
    __syncthreads();
#pragma unroll
    for (int j = 0; j < 2; j++) {
        int c = t + 512 * j;
        y0[c] = (u[c] - mu) * r * ld1(g0, c, ISF) + ld1(be0, c, ISF);
    }
    __syncthreads();

    float yr[16];
    if constexpr (ISF) {
#pragma unroll
        for (int e = 0; e < 16; e++) yr[e] = y0[lane * 16 + e];
    } else {
#pragma unroll
        for (int e = 0; e < 8; e++) { yr[e] = y0[lane * 8 + e]; yr[8 + e] = y0[512 + lane * 8 + e]; }
    }
    for (int i = 0; i < 128; i++) {
        int n = i * 8 + w;
        float p = 0.f;
        if constexpr (ISF) {
            float wv[8];
            const float* row = (const float*)Wo + (size_t)n * DVX;
            ld8<true>(row, lane * 16, wv);
#pragma unroll
            for (int e = 0; e < 8; e++) p += wv[e] * yr[e];
            ld8<true>(row, lane * 16 + 8, wv);
#pragma unroll
            for (int e = 0; e < 8; e++) p += wv[e] * yr[8 + e];
        } else {
            const uint4* row = (const uint4*)((const u16*)Wo + (size_t)n * DVX);
            uint4 v0 = row[lane], v1 = row[lane + 64];
            p += bfu(v0.x & 0xffff) * yr[0] + bfu(v0.x >> 16) * yr[1]
               + bfu(v0.y & 0xffff) * yr[2] + bfu(v0.y >> 16) * yr[3]
               + bfu(v0.z & 0xffff) * yr[4] + bfu(v0.z >> 16) * yr[5]
               + bfu(v0.w & 0xffff) * yr[6] + bfu(v0.w >> 16) * yr[7];
            p += bfu(v1.x & 0xffff) * yr[8]  + bfu(v1.x >> 16) * yr[9]
               + bfu(v1.y & 0xffff) * yr[10] + bfu(v1.y >> 16) * yr[11]
               + bfu(v1.z & 0xffff) * yr[12] + bfu(v1.z >> 16) * yr[13]
               + bfu(v1.w & 0xffff) * yr[14] + bfu(v1.w >> 16) * yr[15];
        }
#pragma unroll
        for (int off = 32; off > 0; off >>= 1)
            p += __shfl_xor(p, off, 64);
        if (lane == 0) {
            float z = p + ld1(bo, n, ISF);
            u[n] = y0[n] + fmaxf(z, 0.f);     // reuse u as y1
        }
    }
    __syncthreads();
    ls = 0.f; ls2 = 0.f;
#pragma unroll
    for (int j = 0; j < 2; j++) {
        int c = t + 512 * j; float v = u[c]; ls += v; ls2 += v * v;
    }
    red[t] = ls; __syncthreads();
    for (int s2 = 256; s2 > 0; s2 >>= 1) { if (t < s2) red[t] += red[t + s2]; __syncthreads(); }
    mu = red[0] / DVX; __syncthreads();
    red[t] = ls2; __syncthreads();
    for (int s2 = 256; s2 > 0; s2 >>= 1) { if (t < s2) red[t] += red[t + s2]; __syncthreads(); }
    var = red[0] / DVX - mu * mu;
    r = rsqrtf(var + EPSF);
#pragma unroll
    for (int j = 0; j < 2; j++) {
        int c = t + 512 * j;
        float v = (u[c] - mu) * r * ld1(g1, c, ISF) + ld1(be1, c, ISF);
        if (ISF) ((float*)out)[(size_t)bq * DVX + c] = v;
        else     ((u16*)out)[(size_t)bq * DVX + c] = f2b(v);
    }
}

__global__ __launch_bounds__(512) void epi_kernel(
        const int* __restrict__ flag,
        const float* __restrict__ Oat, const void* __restrict__ S,
        const void* __restrict__ Wo, const void* __restrict__ bo,
        const void* __restrict__ g0, const void* __restrict__ be0,
        const void* __restrict__ g1, const void* __restrict__ be1,
        void* __restrict__ out) {
    __shared__ float u[DVX];
    __shared__ float y0[DVX];
    __shared__ float red[512];
    if (*flag) epi_body<true>(u, y0, red, Oat, S, Wo, bo, g0, be0, g1, be1, out);
    else       epi_body<false>(u, y0, red, Oat, S, Wo, bo, g0, be0, g1, be1, out);
}

extern "C" void kernel_launch(void* const* d_in, const int* in_sizes, int n_in,
                              void* d_out, int out_size, void* d_ws, size_t ws_size,
                              hipStream_t stream) {
    (void)in_sizes; (void)n_in; (void)out_size;
    const void* X    = d_in[0];
    const int* pad   = (const int*)d_in[1];
    const void* S    = d_in[2];
    const void* Wq   = d_in[3];
    const void* bq   = d_in[4];
    const void* Wk   = d_in[5];
    const void* bk   = d_in[6];
    const void* Wv   = d_in[7];
    const void* bv   = d_in[8];
    const void* Wo   = d_in[9];
    const void* bo   = d_in[10];
    const void* g0   = d_in[11];
    const void* be0  = d_in[12];
    const void* g1   = d_in[13];
    const void* be1  = d_in[14];

    char* ws = (char*)d_ws;
    int*   flag = (int*)ws;                                // 256 B reserved
    float* Qp  = (float*)(ws + 256);                       // 128 KiB
    float* Oat = (float*)(ws + 256 + 131072);              // 1 MiB
    u16*   Kp  = (u16*)(ws + 256 + 131072 + 1048576);      // 32 MiB
    u16*   Vp  = Kp + (size_t)BX * LX * DVX;               // 32 MiB
    u16*   Xb  = Vp + (size_t)BX * LX * DVX;               // 128 MiB (bf16 X)
    u16*   Wkb = Xb + (size_t)BX * LX * DIMX;              // 8 MiB
    u16*   Wvb = Wkb + (size_t)DVX * DIMX;                 // 8 MiB
    float* Opart = (float*)(Wvb + (size_t)DVX * DIMX);     // 8 MiB
    float* Ml  = Opart + (size_t)BX * HX * NCH * NSX * DHX; // 256 KiB

    size_t need = 256 + 131072 + 1048576
                + 2 * (size_t)BX * LX * DVX * 2
                + (size_t)BX * LX * DIMX * 2
                + 2 * (size_t)DVX * DIMX * 2;              // ~209 MiB
    size_t need2 = need
                 + (size_t)BX * HX * NCH * NSX * DHX * 4   // Opart
                 + (size_t)BX * HX * NCH * 64 * 4;         // Ml

    static int attr_ok = -1;
    if (attr_ok < 0) {
        hipError_t e = hipFuncSetAttribute(
            reinterpret_cast<const void*>(kv_gemm3),
            hipFuncAttributeMaxDynamicSharedMemorySize, 131072);
        attr_ok = (e == hipSuccess) ? 1 : 0;
    }

    detect_kernel<<<1, 256, 0, stream>>>((const u16*)X, flag);
    qp_kernel<<<8192, 256, 0, stream>>>(flag, S, Wq, bq, Qp);

    if (ws_size >= need) {
        cvt_kernel<<<2048, 256, 0, stream>>>(flag, (const float*)X, Xb,
                                             BX * LX * DIMX / 8);
        cvt_kernel<<<512, 256, 0, stream>>>(flag, (const float*)Wk, Wkb,
                                            DVX * DIMX / 8);
        cvt_kernel<<<512, 256, 0, stream>>>(flag, (const float*)Wv, Wvb,
                                            DVX * DIMX / 8);
        if (attr_ok == 1) {
            kv_gemm3<<<512, 512, 131072, stream>>>(flag, X, Xb, Wk, bk, Wv, bv,
                                                   Wkb, Wvb, Kp, Vp);
        } else {
            kv_gemm2<<<2048, 256, 0, stream>>>(flag, X, Xb, Wk, bk, Wv, bv,
                                               Wkb, Wvb, Kp, Vp);
        }
    } else {
        kv_gemm<<<2048, 256, 0, stream>>>(flag, X, Wk, bk, Wv, bv, Kp, Vp);
    }

    if (ws_size >= need2) {
        attn2_kernel<<<BX * HX * NCH, 256, 0, stream>>>(Qp, Kp, Vp, pad,
                                                        Opart, Ml);
        attn_combine<<<BX * HX, 256, 0, stream>>>(Opart, Ml, Oat);
    } else {
        attn_kernel<<<BX * HX * (NSX / QG), 256, 0, stream>>>(Qp, Kp, Vp, pad, Oat);
    }
    epi_kernel<<<BX * NSX, 512, 0, stream>>>(flag, Oat, S, Wo, bo, g0, be0, g1, be1, (void*)d_out);
}

// Round 5
// 852.361 us; speedup vs baseline: 1.4052x; 1.0407x over previous
//
#include <hip/hip_runtime.h>

#define DIMX 4096
#define DVX  1024
#define HX   16
#define DHX  64
#define NSX  32
#define BX   8
#define LX   2048
#define EPSF 1e-5f

typedef unsigned short u16;
typedef unsigned int   u32;

using bf16x8 = __attribute__((ext_vector_type(8))) __bf16;
using f32x4  = __attribute__((ext_vector_type(4))) float;

__device__ __forceinline__ float bfu(u16 u) {
    union { u32 i; float f; } c; c.i = ((u32)u) << 16; return c.f;
}
__device__ __forceinline__ u16 f2b(float f) {
    union { float f; u32 u; } c; c.f = f;
    u32 u = c.u;
    u32 r = (u + 0x7fffu + ((u >> 16) & 1u)) >> 16;
    return (u16)r;
}

// async global->LDS DMA, 16B per lane; LDS dest = wave-uniform base + lane*16
__device__ __forceinline__ void async16(const u16* g, u16* l) {
    __builtin_amdgcn_global_load_lds(
        (const __attribute__((address_space(1))) void*)g,
        (__attribute__((address_space(3))) void*)l, 16, 0, 0);
}

// load 8 logical elements (idx multiple of 8, 16B-aligned base) as fp32
template<bool ISF>
__device__ __forceinline__ void ld8(const void* base, size_t idx, float o[8]) {
    if (ISF) {
        const float* f = (const float*)base + idx;
        float4 a = *(const float4*)f, b = *(const float4*)(f + 4);
        o[0]=a.x; o[1]=a.y; o[2]=a.z; o[3]=a.w;
        o[4]=b.x; o[5]=b.y; o[6]=b.z; o[7]=b.w;
    } else {
        const u16* h = (const u16*)base + idx;
        uint4 v = *(const uint4*)h;
        o[0]=bfu(v.x & 0xffff); o[1]=bfu(v.x >> 16);
        o[2]=bfu(v.y & 0xffff); o[3]=bfu(v.y >> 16);
        o[4]=bfu(v.z & 0xffff); o[5]=bfu(v.z >> 16);
        o[6]=bfu(v.w & 0xffff); o[7]=bfu(v.w >> 16);
    }
}
__device__ __forceinline__ float ld1(const void* base, size_t idx, bool isf) {
    return isf ? ((const float*)base)[idx] : bfu(((const u16*)base)[idx]);
}

// ---------------- K0: dtype detector -------------------------------------
__global__ __launch_bounds__(256) void detect_kernel(const u16* __restrict__ X,
                                                     int* __restrict__ flag) {
    __shared__ int cnt;
    if (threadIdx.x == 0) cnt = 0;
    __syncthreads();
    int local = 0;
    for (int i = threadIdx.x; i < 8192; i += 256) {
        u32 e = ((u32)X[i] >> 7) & 0xffu;
        if (e >= 200u) local++;
    }
    atomicAdd(&cnt, local);
    __syncthreads();
    if (threadIdx.x == 0) *flag = (cnt > 32) ? 1 : 0;
}

// ---------------- K0b: fp32 -> bf16 bulk converter -------------------------
__global__ __launch_bounds__(256) void cvt_kernel(const int* __restrict__ flag,
                                                  const float* __restrict__ src,
                                                  u16* __restrict__ dst, int ngrp) {
    if (*flag == 0) return;
    int stride = gridDim.x * 256;
    for (int i = blockIdx.x * 256 + threadIdx.x; i < ngrp; i += stride) {
        const float4* f = (const float4*)(src + (size_t)i * 8);
        float4 a = f[0], b = f[1];
        uint4 r;
        r.x = (u32)f2b(a.x) | ((u32)f2b(a.y) << 16);
        r.y = (u32)f2b(a.z) | ((u32)f2b(a.w) << 16);
        r.z = (u32)f2b(b.x) | ((u32)f2b(b.y) << 16);
        r.w = (u32)f2b(b.z) | ((u32)f2b(b.w) << 16);
        *(uint4*)(dst + (size_t)i * 8) = r;
    }
}

// ---------------- K1: Qp = S @ Wq^T + bq  -- wave-per-output GEMV ----------
// fp32 path: contiguous float4 per instruction (lane-consecutive), not the
// old 64B-strided pattern (which cost 64 segments/instr in the TA).
__global__ __launch_bounds__(256) void qp_kernel(
        const int* __restrict__ flag, const void* __restrict__ S,
        const void* __restrict__ Wq, const void* __restrict__ bq,
        float* __restrict__ Qp) {
    int wid = blockIdx.x * 4 + (threadIdx.x >> 6);   // 0..32767
    int lane = threadIdx.x & 63;
    int q = wid >> 10, n = wid & 1023;
    bool isf = (*flag != 0);
    float p = 0.f;
    if (isf) {
        const float4* s4 = (const float4*)((const float*)S + (size_t)q * DVX);
        const float4* w4 = (const float4*)((const float*)Wq + (size_t)n * DVX);
#pragma unroll
        for (int e = 0; e < 4; e++) {
            float4 a = s4[e * 64 + lane];
            float4 b = w4[e * 64 + lane];
            p += a.x * b.x + a.y * b.y + a.z * b.z + a.w * b.w;
        }
    } else {
        const u16* srow = (const u16*)S + (size_t)q * DVX + lane * 16;
        const u16* wrow = (const u16*)Wq + (size_t)n * DVX + lane * 16;
#pragma unroll
        for (int c = 0; c < 2; c++) {
            uint4 a = *(const uint4*)(srow + c * 8);
            uint4 b = *(const uint4*)(wrow + c * 8);
            p += bfu(a.x & 0xffff) * bfu(b.x & 0xffff) + bfu(a.x >> 16) * bfu(b.x >> 16)
               + bfu(a.y & 0xffff) * bfu(b.y & 0xffff) + bfu(a.y >> 16) * bfu(b.y >> 16)
               + bfu(a.z & 0xffff) * bfu(b.z & 0xffff) + bfu(a.z >> 16) * bfu(b.z >> 16)
               + bfu(a.w & 0xffff) * bfu(b.w & 0xffff) + bfu(a.w >> 16) * bfu(b.w >> 16);
        }
    }
#pragma unroll
    for (int off = 32; off > 0; off >>= 1)
        p += __shfl_xor(p, off, 64);
    if (lane == 0) Qp[wid] = p + ld1(bq, n, isf);
}

// ---------------- K2a: 256x256 BK=64 GEMM, 1 sync per K-tile ---------------
// v2: the 4 intra-tile barriers of the phase template protected nothing in
// this drain-0 design (phases only read the landed buffer; stages target the
// other buffer) and cost a barrier convoy. Now: stages issued at tile top
// (max issue->wait distance), waves free-run through all 4 m-quadrants, one
// {sched_barrier; vmcnt(0); s_barrier} per tile.
__global__ __launch_bounds__(512, 2) void kv_gemm3(
        const int* __restrict__ flag,
        const void* __restrict__ X,  const u16* __restrict__ Xb,
        const void* __restrict__ Wk, const void* __restrict__ bk,
        const void* __restrict__ Wv, const void* __restrict__ bv,
        const u16* __restrict__ Wkb, const u16* __restrict__ Wvb,
        u16* __restrict__ Kp, u16* __restrict__ Vp) {
    extern __shared__ __align__(16) u16 lds[];   // 65536 elems = 128 KiB
    const bool isf = (*flag != 0);
    const u16* Xs = isf ? Xb : (const u16*)X;

    const int t = threadIdx.x;
    const int lane = t & 63, w = t >> 6;
    const int wm = w >> 2, wn = w & 3;
    const int quad = lane >> 4, l16 = lane & 15;
    const int l8 = l16 & 7;

    const int bid = blockIdx.x;
    const int swz = (bid & 7) * 64 + (bid >> 3);
    const int mt = swz >> 3, nt = swz & 7;
    const int m0 = mt * 256, n0 = nt * 256;

    const u16* Wb16; const void* bias; int boff;
    if (n0 < DVX) { Wb16 = (isf ? Wkb : (const u16*)Wk) + (size_t)n0 * DIMX;
                    bias = bk; boff = n0; }
    else          { Wb16 = (isf ? Wvb : (const u16*)Wv) + (size_t)(n0 - DVX) * DIMX;
                    bias = bv; boff = n0 - DVX; }

    f32x4 acc[8][4];
#pragma unroll
    for (int i = 0; i < 8; i++)
#pragma unroll
        for (int j = 0; j < 4; j++) acc[i][j] = {0.f, 0.f, 0.f, 0.f};

    // --- prologue: stage tile 0 into buffer 0 ---
    {
        u16* An = lds;
        u16* Bn = lds + 32768;
#pragma unroll
        for (int i = 0; i < 4; i++) {
            int gi = i * 512 + t;
            int r = gi >> 3;
            int g = (gi & 7) ^ (r & 7);
            async16(Xs + (size_t)(m0 + r) * DIMX + g * 8, An + gi * 8);
        }
#pragma unroll
        for (int i = 0; i < 4; i++) {
            int gi = i * 512 + t;
            int r = gi >> 3;
            int g = (gi & 7) ^ (r & 7);
            async16(Wb16 + (size_t)r * DIMX + g * 8, Bn + gi * 8);
        }
        asm volatile("s_waitcnt vmcnt(0)" ::: "memory");
        __builtin_amdgcn_s_barrier();
    }

    for (int kt = 0; kt < DIMX / 64; kt++) {
        u16* Ab = lds + (kt & 1) * 16384;
        u16* Bb = lds + 32768 + (kt & 1) * 16384;
        u16* An = lds + ((kt + 1) & 1) * 16384;
        u16* Bn = lds + 32768 + ((kt + 1) & 1) * 16384;
        const int k1 = (kt + 1) * 64;

        // ---- stage next tile FIRST: ~full tile of MFMA covers the latency
        if (kt + 1 < DIMX / 64) {
#pragma unroll
            for (int i = 0; i < 4; i++) {
                int gi = i * 512 + t;
                int r = gi >> 3;
                int g = (gi & 7) ^ (r & 7);
                async16(Xs + (size_t)(m0 + r) * DIMX + k1 + g * 8, An + gi * 8);
            }
#pragma unroll
            for (int i = 0; i < 4; i++) {
                int gi = i * 512 + t;
                int r = gi >> 3;
                int g = (gi & 7) ^ (r & 7);
                async16(Wb16 + (size_t)r * DIMX + k1 + g * 8, Bn + gi * 8);
            }
        }
        __builtin_amdgcn_sched_barrier(0);   // pin stage issues before compute

        // ---- B fragments once per tile ----
        bf16x8 bfr[4][2];
#pragma unroll
        for (int ni = 0; ni < 4; ni++)
#pragma unroll
            for (int ks = 0; ks < 2; ks++) {
                int R = wn * 64 + ni * 16 + l16;
                int cc = ((ks * 4 + quad) ^ l8);
                bfr[ni][ks] = *(const bf16x8*)&Bb[R * 64 + cc * 8];
            }

        // ---- 4 m-quadrants, free-running (no intra-tile barriers) ----
#pragma unroll
        for (int p = 0; p < 4; p++) {
            bf16x8 a[2][2];
#pragma unroll
            for (int dm = 0; dm < 2; dm++)
#pragma unroll
                for (int ks = 0; ks < 2; ks++) {
                    int R = wm * 128 + (2 * p + dm) * 16 + l16;
                    int cc = ((ks * 4 + quad) ^ l8);
                    a[dm][ks] = *(const bf16x8*)&Ab[R * 64 + cc * 8];
                }
            __builtin_amdgcn_s_setprio(1);
#pragma unroll
            for (int dm = 0; dm < 2; dm++)
#pragma unroll
                for (int ni = 0; ni < 4; ni++)
#pragma unroll
                    for (int ks = 0; ks < 2; ks++)
                        acc[2 * p + dm][ni] = __builtin_amdgcn_mfma_f32_16x16x32_bf16(
                            a[dm][ks], bfr[ni][ks], acc[2 * p + dm][ni], 0, 0, 0);
            __builtin_amdgcn_s_setprio(0);
        }

        // ---- single per-tile sync: next buffer landed, everyone done ----
        __builtin_amdgcn_sched_barrier(0);
        asm volatile("s_waitcnt vmcnt(0)" ::: "memory");
        __builtin_amdgcn_s_barrier();
        __builtin_amdgcn_sched_barrier(0);
    }

    float bb[4];
#pragma unroll
    for (int ni = 0; ni < 4; ni++)
        bb[ni] = ld1(bias, (size_t)(boff + wn * 64 + ni * 16 + l16), isf);
#pragma unroll
    for (int mi = 0; mi < 8; mi++) {
#pragma unroll
        for (int ni = 0; ni < 4; ni++) {
            int colL = wn * 64 + ni * 16 + l16;
            int col = n0 + colL;
            u16* dst; int dcol;
            if (col < DVX) { dst = Kp; dcol = col; }
            else           { dst = Vp; dcol = col - DVX; }
#pragma unroll
            for (int r = 0; r < 4; r++) {
                int row = m0 + wm * 128 + mi * 16 + quad * 4 + r;
                dst[(size_t)row * DVX + dcol] = f2b(acc[mi][ni][r] + bb[ni]);
            }
        }
    }
}

// ---------------- K2b: 128x128 m97-structure GEMM (fallback fast path) -----
#define TM 128
#define TN 128
#define BKK 32
#define LDT 32

__device__ __forceinline__ uint4 pack8(float o[8]) {
    uint4 r;
    r.x = (u32)f2b(o[0]) | ((u32)f2b(o[1]) << 16);
    r.y = (u32)f2b(o[2]) | ((u32)f2b(o[3]) << 16);
    r.z = (u32)f2b(o[4]) | ((u32)f2b(o[5]) << 16);
    r.w = (u32)f2b(o[6]) | ((u32)f2b(o[7]) << 16);
    return r;
}

__global__ __launch_bounds__(256) void kv_gemm2(
        const int* __restrict__ flag,
        const void* __restrict__ X,  const u16* __restrict__ Xb,
        const void* __restrict__ Wk, const void* __restrict__ bk,
        const void* __restrict__ Wv, const void* __restrict__ bv,
        const u16* __restrict__ Wkb, const u16* __restrict__ Wvb,
        u16* __restrict__ Kp, u16* __restrict__ Vp) {
    __shared__ u16 As[TM * LDT];
    __shared__ u16 Bs[TN * LDT];
    const bool isf = (*flag != 0);
    const u16* Xs = isf ? Xb : (const u16*)X;

    const int t = threadIdx.x;
    const int lane = t & 63, w = t >> 6;
    const int wm = w >> 1, wn = w & 1;
    const int quad = lane >> 4, l16 = lane & 15;
    const int bl = blockIdx.x;
    const int xcd = bl & 7, bq = bl >> 3;
    const int m0 = (xcd + 8 * (bq >> 4)) * TM;
    const int n0 = (bq & 15) * TN;
    const u16* Wb16; const void* bias; int boff;
    if (n0 < DVX) { Wb16 = (isf ? Wkb : (const u16*)Wk) + (size_t)n0 * DIMX;
                    bias = bk; boff = n0; }
    else          { Wb16 = (isf ? Wvb : (const u16*)Wv) + (size_t)(n0 - DVX) * DIMX;
                    bias = bv; boff = n0 - DVX; }

    f32x4 acc[4][4];
#pragma unroll
    for (int i = 0; i < 4; i++)
#pragma unroll
        for (int j = 0; j < 4; j++) acc[i][j] = {0.f, 0.f, 0.f, 0.f};

    const int srow = lane >> 2;
    const int gcol = ((lane & 3) ^ ((lane >> 3) & 3)) * 8;
    const int ph = (l16 >> 1) & 3;

    for (int k0 = 0; k0 < DIMX; k0 += BKK) {
        __syncthreads();
#pragma unroll
        for (int c = 0; c < 2; c++) {
            int rr = w * 32 + c * 16;
            async16(Xs + (size_t)(m0 + rr + srow) * DIMX + k0 + gcol,
                    As + rr * LDT);
            async16(Wb16 + (size_t)(rr + srow) * DIMX + k0 + gcol,
                    Bs + rr * LDT);
        }
        __syncthreads();
        bf16x8 af[4], bfr[4];
#pragma unroll
        for (int mi = 0; mi < 4; mi++) {
            int ar = wm * 64 + mi * 16 + l16;
            af[mi] = *(const bf16x8*)&As[ar * LDT + (quad ^ ph) * 8];
        }
#pragma unroll
        for (int ni = 0; ni < 4; ni++) {
            int br = wn * 64 + ni * 16 + l16;
            bfr[ni] = *(const bf16x8*)&Bs[br * LDT + (quad ^ ph) * 8];
        }
#pragma unroll
        for (int mi = 0; mi < 4; mi++)
#pragma unroll
            for (int ni = 0; ni < 4; ni++)
                acc[mi][ni] = __builtin_amdgcn_mfma_f32_16x16x32_bf16(
                    af[mi], bfr[ni], acc[mi][ni], 0, 0, 0);
    }

#pragma unroll
    for (int mi = 0; mi < 4; mi++) {
#pragma unroll
        for (int ni = 0; ni < 4; ni++) {
            int colL = wn * 64 + ni * 16 + l16;
            int col = n0 + colL;
            float bb = ld1(bias, (size_t)(boff + colL), isf);
            u16* dst; int dcol;
            if (col < DVX) { dst = Kp; dcol = col; }
            else           { dst = Vp; dcol = col - DVX; }
#pragma unroll
            for (int r = 0; r < 4; r++) {
                int row = m0 + wm * 64 + mi * 16 + quad * 4 + r;
                dst[(size_t)row * DVX + dcol] = f2b(acc[mi][ni][r] + bb);
            }
        }
    }
}

// -------- fallback path (small workspace): original dual-dtype body --------
template<bool ISF>
__device__ void kv_body(const void* __restrict__ X,
                        const void* __restrict__ Wk, const void* __restrict__ bk,
                        const void* __restrict__ Wv, const void* __restrict__ bv,
                        u16* __restrict__ Kp, u16* __restrict__ Vp,
                        u16* As, u16* Bs) {
    const int t = threadIdx.x;
    const int lane = t & 63, w = t >> 6;
    const int wm = w >> 1, wn = w & 1;
    const int quad = lane >> 4, l16 = lane & 15;
    const int bl = blockIdx.x;
    const int xcd = bl & 7, bq = bl >> 3;
    const int m0 = (xcd + 8 * (bq >> 4)) * TM;
    const int n0 = (bq & 15) * TN;
    const void* Wbase; const void* bias; int boff;
    size_t woff;
    if (n0 < DVX) { Wbase = Wk; bias = bk; woff = (size_t)n0 * DIMX; boff = n0; }
    else          { Wbase = Wv; bias = bv; woff = (size_t)(n0 - DVX) * DIMX; boff = n0 - DVX; }
    const u16* Wb16 = (const u16*)Wbase + woff;
    const float* Wbf = (const float*)Wbase + woff;

    f32x4 acc[4][4];
#pragma unroll
    for (int i = 0; i < 4; i++)
#pragma unroll
        for (int j = 0; j < 4; j++) acc[i][j] = {0.f, 0.f, 0.f, 0.f};

    const int srow = lane >> 2;
    const int gcol = ((lane & 3) ^ ((lane >> 3) & 3)) * 8;
    const int ph = (l16 >> 1) & 3;
    const int r0 = t >> 2, c0 = (t & 3) * 8;
    const int r1 = r0 + 64;
    const int swc = (((t & 3) ^ ((r0 >> 1) & 3))) * 8;

    for (int k0 = 0; k0 < DIMX; k0 += BKK) {
        if constexpr (ISF) {
            float oa0[8], oa1[8], ob0[8], ob1[8];
            ld8<true>(X,   (size_t)(m0 + r0) * DIMX + k0 + c0, oa0);
            ld8<true>(X,   (size_t)(m0 + r1) * DIMX + k0 + c0, oa1);
            ld8<true>(Wbf, (size_t)r0 * DIMX + k0 + c0, ob0);
            ld8<true>(Wbf, (size_t)r1 * DIMX + k0 + c0, ob1);
            __syncthreads();
            *(uint4*)&As[r0 * LDT + swc] = pack8(oa0);
            *(uint4*)&As[r1 * LDT + swc] = pack8(oa1);
            *(uint4*)&Bs[r0 * LDT + swc] = pack8(ob0);
            *(uint4*)&Bs[r1 * LDT + swc] = pack8(ob1);
        } else {
            __syncthreads();
#pragma unroll
            for (int c = 0; c < 2; c++) {
                int rr = w * 32 + c * 16;
                async16((const u16*)X + (size_t)(m0 + rr + srow) * DIMX + k0 + gcol,
                        As + rr * LDT);
                async16(Wb16 + (size_t)(rr + srow) * DIMX + k0 + gcol,
                        Bs + rr * LDT);
            }
        }
        __syncthreads();
        bf16x8 af[4], bfr[4];
#pragma unroll
        for (int mi = 0; mi < 4; mi++) {
            int ar = wm * 64 + mi * 16 + l16;
            af[mi] = *(const bf16x8*)&As[ar * LDT + (quad ^ ph) * 8];
        }
#pragma unroll
        for (int ni = 0; ni < 4; ni++) {
            int br = wn * 64 + ni * 16 + l16;
            bfr[ni] = *(const bf16x8*)&Bs[br * LDT + (quad ^ ph) * 8];
        }
#pragma unroll
        for (int mi = 0; mi < 4; mi++)
#pragma unroll
            for (int ni = 0; ni < 4; ni++)
                acc[mi][ni] = __builtin_amdgcn_mfma_f32_16x16x32_bf16(
                    af[mi], bfr[ni], acc[mi][ni], 0, 0, 0);
    }

#pragma unroll
    for (int mi = 0; mi < 4; mi++) {
#pragma unroll
        for (int ni = 0; ni < 4; ni++) {
            int colL = wn * 64 + ni * 16 + l16;
            int col = n0 + colL;
            float bb = ld1(bias, (size_t)(boff + colL), ISF);
            u16* dst; int dcol;
            if (col < DVX) { dst = Kp; dcol = col; }
            else           { dst = Vp; dcol = col - DVX; }
#pragma unroll
            for (int r = 0; r < 4; r++) {
                int row = m0 + wm * 64 + mi * 16 + quad * 4 + r;
                dst[(size_t)row * DVX + dcol] = f2b(acc[mi][ni][r] + bb);
            }
        }
    }
}

__global__ __launch_bounds__(256) void kv_gemm(
        const int* __restrict__ flag, const void* __restrict__ X,
        const void* __restrict__ Wk, const void* __restrict__ bk,
        const void* __restrict__ Wv, const void* __restrict__ bv,
        u16* __restrict__ Kp, u16* __restrict__ Vp) {
    __shared__ u16 As[TM * LDT];
    __shared__ u16 Bs[TN * LDT];
    if (*flag) kv_body<true>(X, Wk, bk, Wv, bv, Kp, Vp, As, Bs);
    else       kv_body<false>(X, Wk, bk, Wv, bv, Kp, Vp, As, Bs);
}

// ---------------- K3a: split-K attention chunk kernel ----------------------
#define CHK 256
#define NCH (LX / CHK)                      // 8
__global__ __launch_bounds__(256) void attn2_kernel(
        const float* __restrict__ Qp, const u16* __restrict__ Kp,
        const u16* __restrict__ Vp, const int* __restrict__ pad,
        float* __restrict__ Opart, float* __restrict__ Ml) {
    __shared__ float sc[NSX * CHK];         // 32 KB
    const int blk = blockIdx.x;             // b*HX*NCH + h*NCH + c0
    const int b  = blk / (HX * NCH);
    const int h  = (blk / NCH) % HX;
    const int c0 = blk % NCH;
    const int t = threadIdx.x;
    const int w = t >> 6, lane = t & 63;
    const int rsub = lane >> 3;             // key row within octet (0..7)
    const int dsub = lane & 7;              // d-chunk (0..7)
    const int q0w = w * 8;                  // this wave's 8 queries

    float qc[8][8];
#pragma unroll
    for (int qq = 0; qq < 8; qq++) {
        const float* qp = Qp + (size_t)(q0w + qq) * DVX + h * DHX + dsub * 8;
        float4 a = *(const float4*)qp, bq4 = *(const float4*)(qp + 4);
        qc[qq][0]=a.x; qc[qq][1]=a.y; qc[qq][2]=a.z; qc[qq][3]=a.w;
        qc[qq][4]=bq4.x; qc[qq][5]=bq4.y; qc[qq][6]=bq4.z; qc[qq][7]=bq4.w;
    }

    const u16* kb = Kp + ((size_t)b * LX + c0 * CHK) * DVX + h * DHX;
    const int* pb = pad + b * LX + c0 * CHK;

    float lmax[8];
#pragma unroll
    for (int qq = 0; qq < 8; qq++) lmax[qq] = -3e38f;
    for (int i = 0; i < CHK / 8; i++) {
        int k = i * 8 + rsub;
        uint4 v = *(const uint4*)(kb + (size_t)k * DVX + dsub * 8);
        float kf[8];
        kf[0]=bfu(v.x & 0xffff); kf[1]=bfu(v.x >> 16);
        kf[2]=bfu(v.y & 0xffff); kf[3]=bfu(v.y >> 16);
        kf[4]=bfu(v.z & 0xffff); kf[5]=bfu(v.z >> 16);
        kf[6]=bfu(v.w & 0xffff); kf[7]=bfu(v.w >> 16);
        int pm = pb[k];
#pragma unroll
        for (int qq = 0; qq < 8; qq++) {
            float s = kf[0]*qc[qq][0] + kf[1]*qc[qq][1]
                    + kf[2]*qc[qq][2] + kf[3]*qc[qq][3]
                    + kf[4]*qc[qq][4] + kf[5]*qc[qq][5]
                    + kf[6]*qc[qq][6] + kf[7]*qc[qq][7];
            s += __shfl_xor(s, 1, 64);
            s += __shfl_xor(s, 2, 64);
            s += __shfl_xor(s, 4, 64);
            s *= 0.03125f;
            s = pm ? s : -1e30f;
            if (dsub == 0) sc[(q0w + qq) * CHK + k] = s;
            lmax[qq] = fmaxf(lmax[qq], s);
        }
    }
#pragma unroll
    for (int qq = 0; qq < 8; qq++) {
        lmax[qq] = fmaxf(lmax[qq], __shfl_xor(lmax[qq], 8, 64));
        lmax[qq] = fmaxf(lmax[qq], __shfl_xor(lmax[qq], 16, 64));
        lmax[qq] = fmaxf(lmax[qq], __shfl_xor(lmax[qq], 32, 64));
    }

#pragma unroll
    for (int qq = 0; qq < 8; qq++) {
        float m = lmax[qq];
        float lsum = 0.f;
#pragma unroll
        for (int it = 0; it < CHK / 64; it++) {
            int idx = (q0w + qq) * CHK + it * 64 + lane;
            float sv = sc[idx];
            float e = (sv > -1e29f) ? __expf(sv - m) : 0.f;
            sc[idx] = e;
            lsum += e;
        }
#pragma unroll
        for (int off = 32; off > 0; off >>= 1)
            lsum += __shfl_xor(lsum, off, 64);
        if (lane == 0) {
            Ml[(size_t)blk * 64 + (q0w + qq) * 2 + 0] = m;
            Ml[(size_t)blk * 64 + (q0w + qq) * 2 + 1] = lsum;
        }
    }

    float acc[8][8];
#pragma unroll
    for (int qq = 0; qq < 8; qq++)
#pragma unroll
        for (int e = 0; e < 8; e++) acc[qq][e] = 0.f;
    const u16* vb = Vp + ((size_t)b * LX + c0 * CHK) * DVX + h * DHX + dsub * 8;
    for (int i = 0; i < CHK / 8; i++) {
        int k = i * 8 + rsub;
        uint4 v = *(const uint4*)(vb + (size_t)k * DVX);
        float vf[8];
        vf[0]=bfu(v.x & 0xffff); vf[1]=bfu(v.x >> 16);
        vf[2]=bfu(v.y & 0xffff); vf[3]=bfu(v.y >> 16);
        vf[4]=bfu(v.z & 0xffff); vf[5]=bfu(v.z >> 16);
        vf[6]=bfu(v.w & 0xffff); vf[7]=bfu(v.w >> 16);
#pragma unroll
        for (int qq = 0; qq < 8; qq++) {
            float p = sc[(q0w + qq) * CHK + k];
#pragma unroll
            for (int e = 0; e < 8; e++) acc[qq][e] += p * vf[e];
        }
    }
#pragma unroll
    for (int qq = 0; qq < 8; qq++) {
#pragma unroll
        for (int e = 0; e < 8; e++) {
            acc[qq][e] += __shfl_xor(acc[qq][e], 8, 64);
            acc[qq][e] += __shfl_xor(acc[qq][e], 16, 64);
            acc[qq][e] += __shfl_xor(acc[qq][e], 32, 64);
        }
        if (rsub == qq) {
            float* op = Opart + ((size_t)blk * NSX + q0w + qq) * DHX + dsub * 8;
            float4 r0 = {acc[qq][0], acc[qq][1], acc[qq][2], acc[qq][3]};
            float4 r1 = {acc[qq][4], acc[qq][5], acc[qq][6], acc[qq][7]};
            *(float4*)op = r0;
            *(float4*)(op + 4) = r1;
        }
    }
}

// ---------------- K3b: combine split-K partials ----------------------------
__global__ __launch_bounds__(256) void attn_combine(
        const float* __restrict__ Opart, const float* __restrict__ Ml,
        float* __restrict__ Oat) {
    const int bh = blockIdx.x;              // 0..127
    const int b = bh / HX, h = bh % HX;
    const int t = threadIdx.x;
    const int q = t >> 3, d0 = (t & 7) * 8;
    const size_t cbase = (size_t)bh * NCH;
    float m = -3e38f;
#pragma unroll
    for (int c = 0; c < NCH; c++)
        m = fmaxf(m, Ml[(cbase + c) * 64 + q * 2]);
    float l = 0.f, o[8];
#pragma unroll
    for (int e = 0; e < 8; e++) o[e] = 0.f;
#pragma unroll
    for (int c = 0; c < NCH; c++) {
        float mc = Ml[(cbase + c) * 64 + q * 2 + 0];
        float lc = Ml[(cbase + c) * 64 + q * 2 + 1];
        float wgt = (mc > -1e29f) ? __expf(mc - m) : 0.f;
        l += wgt * lc;
        const float* op = Opart + ((cbase + c) * NSX + q) * DHX + d0;
        float4 x = *(const float4*)op, y = *(const float4*)(op + 4);
        o[0] += wgt * x.x; o[1] += wgt * x.y; o[2] += wgt * x.z; o[3] += wgt * x.w;
        o[4] += wgt * y.x; o[5] += wgt * y.y; o[6] += wgt * y.z; o[7] += wgt * y.w;
    }
    float inv = (l > 0.f) ? 1.f / l : 0.f;
    float* dst = Oat + ((size_t)(b * NSX) + q) * DVX + h * DHX + d0;
    float4 r0 = {o[0]*inv, o[1]*inv, o[2]*inv, o[3]*inv};
    float4 r1 = {o[4]*inv, o[5]*inv, o[6]*inv, o[7]*inv};
    *(float4*)dst = r0;
    *(float4*)(dst + 4) = r1;
}

// ---------------- K3-legacy: old attention (workspace fallback) ------------
#define QG 4
__global__ __launch_bounds__(256) void attn_kernel(
        const float* __restrict__ Qp, const u16* __restrict__ Kp,
        const u16* __restrict__ Vp, const int* __restrict__ pad,
        float* __restrict__ Oat) {
    __shared__ float qv[QG * DHX];
    __shared__ float sc[QG * LX];
    __shared__ float rpart[256 * 8];
    __shared__ float invs[QG];
    const int blk = blockIdx.x;
    const int nqg = NSX / QG;
    const int b  = blk / (HX * nqg);
    const int h  = (blk / nqg) % HX;
    const int q0 = (blk % nqg) * QG;
    const int t = threadIdx.x;
    const int w = t >> 6, lane = t & 63;

    qv[t] = Qp[(size_t)(q0 + (t >> 6)) * DVX + h * DHX + (t & 63)];
    __syncthreads();

    const u16* Kb = Kp + (size_t)b * LX * DVX + h * DHX;
    const int rsub = lane >> 3;
    const int dsub = lane & 7;
    float qc[8];
#pragma unroll
    for (int e = 0; e < 8; e++) qc[e] = qv[w * DHX + dsub * 8 + e];

    float lmax = -3e38f;
    for (int i = 0; i < LX / 8; i++) {
        int k = i * 8 + rsub;
        uint4 v = *(const uint4*)(Kb + (size_t)k * DVX + dsub * 8);
        float s = bfu(v.x & 0xffff) * qc[0] + bfu(v.x >> 16) * qc[1]
                + bfu(v.y & 0xffff) * qc[2] + bfu(v.y >> 16) * qc[3]
                + bfu(v.z & 0xffff) * qc[4] + bfu(v.z >> 16) * qc[5]
                + bfu(v.w & 0xffff) * qc[6] + bfu(v.w >> 16) * qc[7];
        s += __shfl_xor(s, 1, 64);
        s += __shfl_xor(s, 2, 64);
        s += __shfl_xor(s, 4, 64);
        s *= 0.03125f;
        s = (pad[b * LX + k] != 0) ? s : -1e30f;
        if (dsub == 0) sc[w * LX + k] = s;
        lmax = fmaxf(lmax, s);
    }
#pragma unroll
    for (int off = 32; off > 0; off >>= 1)
        lmax = fmaxf(lmax, __shfl_xor(lmax, off, 64));
    float lsum = 0.f;
    for (int i = 0; i < LX / 64; i++) {
        int k = i * 64 + lane;
        float sv = sc[w * LX + k];
        float e = (sv > -1e29f) ? __expf(sv - lmax) : 0.f;
        sc[w * LX + k] = e;
        lsum += e;
    }
#pragma unroll
    for (int off = 32; off > 0; off >>= 1)
        lsum += __shfl_xor(lsum, off, 64);
    if (lane == 0) invs[w] = (lsum > 0.f) ? 1.f / lsum : 0.f;

    const int kg = (t >> 3) & 7, dg = t & 7;
    const u16* Vb = Vp + (size_t)b * LX * DVX + h * DHX + dg * 8;
    float a8[8];
#pragma unroll
    for (int e = 0; e < 8; e++) a8[e] = 0.f;
    for (int i = 0; i < LX / 8; i++) {
        int k = i * 8 + kg;
        float p = sc[w * LX + k];
        uint4 v = *(const uint4*)(Vb + (size_t)k * DVX);
        a8[0] += p * bfu(v.x & 0xffff); a8[1] += p * bfu(v.x >> 16);
        a8[2] += p * bfu(v.y & 0xffff); a8[3] += p * bfu(v.y >> 16);
        a8[4] += p * bfu(v.z & 0xffff); a8[5] += p * bfu(v.z >> 16);
        a8[6] += p * bfu(v.w & 0xffff); a8[7] += p * bfu(v.w >> 16);
    }
#pragma unroll
    for (int e = 0; e < 8; e++) rpart[t * 8 + e] = a8[e];
    __syncthreads();

    {
        int q = t >> 6, d = t & 63;
        float o = 0.f;
#pragma unroll
        for (int g = 0; g < 8; g++)
            o += rpart[(q * 64 + g * 8 + (d >> 3)) * 8 + (d & 7)];
        o *= invs[q];
        Oat[((size_t)(b * NSX + q0 + q)) * DVX + h * DHX + d] = o;
    }
}

// ---------------- K4: residual + LN0 + MLP(relu) residual + LN1 ------------
template<bool ISF>
__device__ void epi_body(float* u, float* y0, float* red,
                         const float* __restrict__ Oat, const void* __restrict__ S,
                         const void* __restrict__ Wo, const void* __restrict__ bo,
                         const void* __restrict__ g0, const void* __restrict__ be0,
                         const void* __restrict__ g1, const void* __restrict__ be1,
                         void* __restrict__ out) {
    const int bq = blockIdx.x;            // (b*32+q)
    const int q = bq & 31;
    const int t = threadIdx.x;
    const int w = t >> 6, lane = t & 63;

    float ls = 0.f, ls2 = 0.f;
#pragma unroll
    for (int j = 0; j < 2; j++) {
        int c = t + 512 * j;
        float v = ld1(S, (size_t)q * DVX + c, ISF) + Oat[(size_t)bq * DVX + c];
        u[c] = v; ls += v; ls2 += v * v;
    }
    red[t] = ls; __syncthreads();
    for (int s2 = 256; s2 > 0; s2 >>= 1) { if (t < s2) red[t] += red[t + s2]; __syncthreads(); }
    float mu = red[0] / DVX; __syncthreads();
    red[t] = ls2; __syncthreads();
    for (int s2 = 256; s2 > 0; s2 >>= 1) { if (t < s2) red[t] += red[t + s2]; __syncthreads(); }
    float var = red[0] / DVX - mu * mu;
    float r = rsqrtf(var + EPSF);
    __syncthreads();
#pragma unroll
    for (int j = 0; j < 2; j++) {
        int c = t + 512 * j;
        y0[c] = (u[c] - mu) * r * ld1(g0, c, ISF) + ld1(be0, c, ISF);
    }
    __syncthreads();

    // GEMV: fp32 path now uses contiguous lane-consecutive float4 loads
    // (old lane*64B-strided pattern = 64 segments per instruction).
    float yr[16];
    if constexpr (ISF) {
        const float4* y4 = (const float4*)y0;
#pragma unroll
        for (int e = 0; e < 4; e++) {
            float4 v = y4[e * 64 + lane];
            yr[e*4+0]=v.x; yr[e*4+1]=v.y; yr[e*4+2]=v.z; yr[e*4+3]=v.w;
        }
    } else {
#pragma unroll
        for (int e = 0; e < 8; e++) { yr[e] = y0[lane * 8 + e]; yr[8 + e] = y0[512 + lane * 8 + e]; }
    }
    for (int i = 0; i < 128; i++) {
        int n = i * 8 + w;
        float p = 0.f;
        if constexpr (ISF) {
            const float4* row4 = (const float4*)((const float*)Wo + (size_t)n * DVX);
#pragma unroll
            for (int e = 0; e < 4; e++) {
                float4 wv = row4[e * 64 + lane];
                p += wv.x * yr[e*4] + wv.y * yr[e*4+1]
                   + wv.z * yr[e*4+2] + wv.w * yr[e*4+3];
            }
        } else {
            const uint4* row = (const uint4*)((const u16*)Wo + (size_t)n * DVX);
            uint4 v0 = row[lane], v1 = row[lane + 64];
            p += bfu(v0.x & 0xffff) * yr[0] + bfu(v0.x >> 16) * yr[1]
               + bfu(v0.y & 0xffff) * yr[2] + bfu(v0.y >> 16) * yr[3]
               + bfu(v0.z & 0xffff) * yr[4] + bfu(v0.z >> 16) * yr[5]
               + bfu(v0.w & 0xffff) * yr[6] + bfu(v0.w >> 16) * yr[7];
            p += bfu(v1.x & 0xffff) * yr[8]  + bfu(v1.x >> 16) * yr[9]
               + bfu(v1.y & 0xffff) * yr[10] + bfu(v1.y >> 16) * yr[11]
               + bfu(v1.z & 0xffff) * yr[12] + bfu(v1.z >> 16) * yr[13]
               + bfu(v1.w & 0xffff) * yr[14] + bfu(v1.w >> 16) * yr[15];
        }
#pragma unroll
        for (int off = 32; off > 0; off >>= 1)
            p += __shfl_xor(p, off, 64);
        if (lane == 0) {
            float z = p + ld1(bo, n, ISF);
            u[n] = y0[n] + fmaxf(z, 0.f);     // reuse u as y1
        }
    }
    __syncthreads();
    ls = 0.f; ls2 = 0.f;
#pragma unroll
    for (int j = 0; j < 2; j++) {
        int c = t + 512 * j; float v = u[c]; ls += v; ls2 += v * v;
    }
    red[t] = ls; __syncthreads();
    for (int s2 = 256; s2 > 0; s2 >>= 1) { if (t < s2) red[t] += red[t + s2]; __syncthreads(); }
    mu = red[0] / DVX; __syncthreads();
    red[t] = ls2; __syncthreads();
    for (int s2 = 256; s2 > 0; s2 >>= 1) { if (t < s2) red[t] += red[t + s2]; __syncthreads(); }
    var = red[0] / DVX - mu * mu;
    r = rsqrtf(var + EPSF);
#pragma unroll
    for (int j = 0; j < 2; j++) {
        int c = t + 512 * j;
        float v = (u[c] - mu) * r * ld1(g1, c, ISF) + ld1(be1, c, ISF);
        if (ISF) ((float*)out)[(size_t)bq * DVX + c] = v;
        else     ((u16*)out)[(size_t)bq * DVX + c] = f2b(v);
    }
}

__global__ __launch_bounds__(512) void epi_kernel(
        const int* __restrict__ flag,
        const float* __restrict__ Oat, const void* __restrict__ S,
        const void* __restrict__ Wo, const void* __restrict__ bo,
        const void* __restrict__ g0, const void* __restrict__ be0,
        const void* __restrict__ g1, const void* __restrict__ be1,
        void* __restrict__ out) {
    __shared__ float u[DVX];
    __shared__ float y0[DVX];
    __shared__ float red[512];
    if (*flag) epi_body<true>(u, y0, red, Oat, S, Wo, bo, g0, be0, g1, be1, out);
    else       epi_body<false>(u, y0, red, Oat, S, Wo, bo, g0, be0, g1, be1, out);
}

extern "C" void kernel_launch(void* const* d_in, const int* in_sizes, int n_in,
                              void* d_out, int out_size, void* d_ws, size_t ws_size,
                              hipStream_t stream) {
    (void)in_sizes; (void)n_in; (void)out_size;
    const void* X    = d_in[0];
    const int* pad   = (const int*)d_in[1];
    const void* S    = d_in[2];
    const void* Wq   = d_in[3];
    const void* bq   = d_in[4];
    const void* Wk   = d_in[5];
    const void* bk   = d_in[6];
    const void* Wv   = d_in[7];
    const void* bv   = d_in[8];
    const void* Wo   = d_in[9];
    const void* bo   = d_in[10];
    const void* g0   = d_in[11];
    const void* be0  = d_in[12];
    const void* g1   = d_in[13];
    const void* be1  = d_in[14];

    char* ws = (char*)d_ws;
    int*   flag = (int*)ws;                                // 256 B reserved
    float* Qp  = (float*)(ws + 256);                       // 128 KiB
    float* Oat = (float*)(ws + 256 + 131072);              // 1 MiB
    u16*   Kp  = (u16*)(ws + 256 + 131072 + 1048576);      // 32 MiB
    u16*   Vp  = Kp + (size_t)BX * LX * DVX;               // 32 MiB
    u16*   Xb  = Vp + (size_t)BX * LX * DVX;               // 128 MiB (bf16 X)
    u16*   Wkb = Xb + (size_t)BX * LX * DIMX;              // 8 MiB
    u16*   Wvb = Wkb + (size_t)DVX * DIMX;                 // 8 MiB
    float* Opart = (float*)(Wvb + (size_t)DVX * DIMX);     // 8 MiB
    float* Ml  = Opart + (size_t)BX * HX * NCH * NSX * DHX; // 256 KiB

    size_t need = 256 + 131072 + 1048576
                + 2 * (size_t)BX * LX * DVX * 2
                + (size_t)BX * LX * DIMX * 2
                + 2 * (size_t)DVX * DIMX * 2;              // ~209 MiB
    size_t need2 = need
                 + (size_t)BX * HX * NCH * NSX * DHX * 4   // Opart
                 + (size_t)BX * HX * NCH * 64 * 4;         // Ml

    static int attr_ok = -1;
    if (attr_ok < 0) {
        hipError_t e = hipFuncSetAttribute(
            reinterpret_cast<const void*>(kv_gemm3),
            hipFuncAttributeMaxDynamicSharedMemorySize, 131072);
        attr_ok = (e == hipSuccess) ? 1 : 0;
    }

    detect_kernel<<<1, 256, 0, stream>>>((const u16*)X, flag);
    qp_kernel<<<8192, 256, 0, stream>>>(flag, S, Wq, bq, Qp);

    if (ws_size >= need) {
        cvt_kernel<<<2048, 256, 0, stream>>>(flag, (const float*)X, Xb,
                                             BX * LX * DIMX / 8);
        cvt_kernel<<<512, 256, 0, stream>>>(flag, (const float*)Wk, Wkb,
                                            DVX * DIMX / 8);
        cvt_kernel<<<512, 256, 0, stream>>>(flag, (const float*)Wv, Wvb,
                                            DVX * DIMX / 8);
        if (attr_ok == 1) {
            kv_gemm3<<<512, 512, 131072, stream>>>(flag, X, Xb, Wk, bk, Wv, bv,
                                                   Wkb, Wvb, Kp, Vp);
        } else {
            kv_gemm2<<<2048, 256, 0, stream>>>(flag, X, Xb, Wk, bk, Wv, bv,
                                               Wkb, Wvb, Kp, Vp);
        }
    } else {
        kv_gemm<<<2048, 256, 0, stream>>>(flag, X, Wk, bk, Wv, bv, Kp, Vp);
    }

    if (ws_size >= need2) {
        attn2_kernel<<<BX * HX * NCH, 256, 0, stream>>>(Qp, Kp, Vp, pad,
                                                        Opart, Ml);
        attn_combine<<<BX * HX, 256, 0, stream>>>(Opart, Ml, Oat);
    } else {
        attn_kernel<<<BX * HX * (NSX / QG), 256, 0, stream>>>(Qp, Kp, Vp, pad, Oat);
    }
    epi_kernel<<<BX * NSX, 512, 0, stream>>>(flag, Oat, S, Wo, bo, g0, be0, g1, be1, (void*)d_out);
}